// Round 5
// baseline (5016.152 us; speedup 1.0000x reference)
//
#include <hip/hip_runtime.h>
#include <math.h>
#include <stdint.h>

#define HD    128      // hidden
#define GATES 512      // 4H
#define BB    64       // batch
#define CL    512      // context len
#define QL    64       // query len

#define TM 128
#define TN 128
#define TK 32

typedef __attribute__((ext_vector_type(8))) short short8_t;
typedef __attribute__((ext_vector_type(4))) short short4_t;
typedef __attribute__((ext_vector_type(4))) float f32x4;

__device__ __forceinline__ float fast_sigmoid(float x) {
    float e = __builtin_amdgcn_exp2f(-1.44269504f * x);
    return __builtin_amdgcn_rcpf(1.f + e);
}
__device__ __forceinline__ float fast_tanh(float x) {
    float e = __builtin_amdgcn_exp2f(2.88539008f * x);
    float r = __builtin_amdgcn_rcpf(e + 1.f);
    return 1.f - 2.f * r;
}

// ---------------------------------------------------------------------------
// Split W (rows=1024, K) fp32 into 3 bf16 planes, each (1024, Ksp), padded.
// ---------------------------------------------------------------------------
__global__ __launch_bounds__(256)
void splitW_k(const float* __restrict__ W, ushort* __restrict__ P, int K, int Ksp)
{
    int idx = blockIdx.x * 256 + threadIdx.x;
    int per_row = Ksp >> 2;
    int total = 1024 * per_row;
    if (idx >= total) return;
    int row = idx / per_row;
    int c4  = (idx - row * per_row) * 4;

    short4_t o1, o2, o3;
#pragma unroll
    for (int e = 0; e < 4; ++e) {
        int k = c4 + e;
        float x = (k < K) ? W[(size_t)row * K + k] : 0.f;
        uint32_t u1 = __float_as_uint(x) & 0xffff0000u;
        float r1 = x - __uint_as_float(u1);
        uint32_t u2 = __float_as_uint(r1) & 0xffff0000u;
        float r2 = r1 - __uint_as_float(u2);
        uint32_t u3 = __float_as_uint(r2) & 0xffff0000u;
        o1[e] = (short)(u1 >> 16);
        o2[e] = (short)(u2 >> 16);
        o3[e] = (short)(u3 >> 16);
    }
    size_t base = (size_t)row * Ksp + c4;
    size_t ps = (size_t)1024 * Ksp;
    *reinterpret_cast<short4_t*>(&P[base]) = o1;
    *reinterpret_cast<short4_t*>(&P[ps + base]) = o2;
    *reinterpret_cast<short4_t*>(&P[2 * ps + base]) = o3;
}

// ---------------------------------------------------------------------------
// MFMA GEMM, bf16x3 split (6 cross-term MFMAs per k-tile).
// ---------------------------------------------------------------------------
__global__ __launch_bounds__(256)
void gemm_bf16x3(const float* __restrict__ A, const int* __restrict__ gidx,
                 const ushort* __restrict__ Wpl, const float* __restrict__ bias,
                 float* __restrict__ C, int M, int K, int Ksp)
{
    const int dir  = blockIdx.z;
    const int m0   = blockIdx.x * TM;
    const int n0   = blockIdx.y * TN;
    const int tid  = threadIdx.x;
    const int lane = tid & 63;
    const int wid  = tid >> 6;
    const int wm   = (wid >> 1) * 64;
    const int wn   = (wid & 1) * 64;

    __shared__ __align__(16) ushort As[3][TM * TK];
    __shared__ __align__(16) ushort Bs[3][TN * TK];

    const int ar = tid >> 3;
    const int ac = (tid & 7) * 4;

    size_t arow[4];
#pragma unroll
    for (int r = 0; r < 4; ++r) {
        int m = m0 + ar + r * 32;
        arow[r] = gidx ? (size_t)gidx[m] : (size_t)m;
    }

    f32x4 acc[4][4];
#pragma unroll
    for (int i = 0; i < 4; ++i)
#pragma unroll
        for (int j = 0; j < 4; ++j) acc[i][j] = (f32x4)0.f;

    const size_t wps    = (size_t)1024 * Ksp;
    const size_t wdbase = (size_t)dir * 512 * Ksp;

    for (int k0 = 0; k0 < Ksp; k0 += TK) {
#pragma unroll
        for (int r = 0; r < 4; ++r) {
            float4 v = make_float4(0.f, 0.f, 0.f, 0.f);
            if (k0 + ac < K) v = *(const float4*)(A + arow[r] * K + k0 + ac);
            float xs[4] = {v.x, v.y, v.z, v.w};
            short4_t o1, o2, o3;
#pragma unroll
            for (int e = 0; e < 4; ++e) {
                uint32_t u1 = __float_as_uint(xs[e]) & 0xffff0000u;
                float r1 = xs[e] - __uint_as_float(u1);
                uint32_t u2 = __float_as_uint(r1) & 0xffff0000u;
                float r2 = r1 - __uint_as_float(u2);
                uint32_t u3 = __float_as_uint(r2) & 0xffff0000u;
                o1[e] = (short)(u1 >> 16);
                o2[e] = (short)(u2 >> 16);
                o3[e] = (short)(u3 >> 16);
            }
            int wb = (ar + r * 32) * TK + ac;
            *reinterpret_cast<short4_t*>(&As[0][wb]) = o1;
            *reinterpret_cast<short4_t*>(&As[1][wb]) = o2;
            *reinterpret_cast<short4_t*>(&As[2][wb]) = o3;
        }
#pragma unroll
        for (int t = 0; t < 6; ++t) {
            int chunk = wid * 6 + t;
            int pl = chunk >> 3;
            int ch = chunk & 7;
            int rrow = ch * 16 + (lane >> 2);
            const ushort* src = Wpl + (size_t)pl * wps + wdbase +
                                (size_t)(n0 + rrow) * Ksp + k0 + (lane & 3) * 8;
            ushort* dst = &Bs[pl][ch * 512];
            __builtin_amdgcn_global_load_lds(
                reinterpret_cast<const __attribute__((address_space(1))) void*>(
                    reinterpret_cast<uintptr_t>(src)),
                reinterpret_cast<__attribute__((address_space(3))) void*>(
                    reinterpret_cast<uintptr_t>(dst)),
                16, 0, 0);
        }
        __syncthreads();

        const int koff = (lane >> 4) * 8;
        short8_t bf0[4], bf1[4], bf2[4];
#pragma unroll
        for (int j = 0; j < 4; ++j) {
            int nrow = wn + j * 16 + (lane & 15);
            bf0[j] = *reinterpret_cast<const short8_t*>(&Bs[0][nrow * TK + koff]);
            bf1[j] = *reinterpret_cast<const short8_t*>(&Bs[1][nrow * TK + koff]);
            bf2[j] = *reinterpret_cast<const short8_t*>(&Bs[2][nrow * TK + koff]);
        }
#pragma unroll
        for (int i = 0; i < 4; ++i) {
            int mrow = wm + i * 16 + (lane & 15);
            short8_t a1 = *reinterpret_cast<const short8_t*>(&As[0][mrow * TK + koff]);
            short8_t a2 = *reinterpret_cast<const short8_t*>(&As[1][mrow * TK + koff]);
            short8_t a3 = *reinterpret_cast<const short8_t*>(&As[2][mrow * TK + koff]);
#pragma unroll
            for (int j = 0; j < 4; ++j) {
                f32x4 c = acc[i][j];
                c = __builtin_amdgcn_mfma_f32_16x16x32_bf16(a1, bf0[j], c, 0, 0, 0);
                c = __builtin_amdgcn_mfma_f32_16x16x32_bf16(a1, bf1[j], c, 0, 0, 0);
                c = __builtin_amdgcn_mfma_f32_16x16x32_bf16(a2, bf0[j], c, 0, 0, 0);
                c = __builtin_amdgcn_mfma_f32_16x16x32_bf16(a2, bf1[j], c, 0, 0, 0);
                c = __builtin_amdgcn_mfma_f32_16x16x32_bf16(a1, bf2[j], c, 0, 0, 0);
                c = __builtin_amdgcn_mfma_f32_16x16x32_bf16(a3, bf0[j], c, 0, 0, 0);
                acc[i][j] = c;
            }
        }
        __syncthreads();
    }

    float* Cd = C + (size_t)dir * M * 512;
#pragma unroll
    for (int j = 0; j < 4; ++j) {
        int col = n0 + wn + j * 16 + (lane & 15);
        float bv = bias[dir * 512 + col];
#pragma unroll
        for (int i = 0; i < 4; ++i) {
            int rbase = m0 + wm + i * 16 + ((lane >> 4) << 2);
#pragma unroll
            for (int r = 0; r < 4; ++r)
                Cd[(size_t)(rbase + r) * 512 + col] = acc[i][j][r] + bv;
        }
    }
}

// ---------------------------------------------------------------------------
// MFMA LSTM scan: 16 chains (batch rows) per block, 512 threads (8 waves).
// Wave w owns hidden cols [w*16, w*16+16) across ALL 4 gates (n = g*128+col),
// so the cell update is entirely in-lane (no pre-act LDS exchange).
// Per step: h(16x128, bf16x2 in LDS) x Whh^T(512x128, bf16x2 in VGPRs) via
// 4-term MFMA; update in registers; h re-split + scattered to the other LDS
// buffer in A-fragment order; ONE barrier per step.
// Whh planes pre-split (splitW_k, Ksp=128; planes 0,1 used).
// ---------------------------------------------------------------------------
__global__ __launch_bounds__(512)
void lstm_mfma(const float* __restrict__ xgP, const ushort* __restrict__ WP2,
               float* __restrict__ hoP, int TP,
               const float* __restrict__ xgQ, const ushort* __restrict__ WQ2,
               float* __restrict__ hoQ, int TQ)
{
    const int cg  = blockIdx.x * 16;        // chain (batch) base
    const int dir = blockIdx.y;
    const int tid = threadIdx.x;
    const int w   = tid >> 6;
    const int l   = tid & 63;
    const int col = w * 16 + (l & 15);      // hidden col 0..127
    const int rb  = (l >> 4) * 4;           // chain row base: 0,4,8,12

    const float* xg; const ushort* WP; float* ho; int T;
    if (blockIdx.z == 0) { xg = xgP; WP = WP2; ho = hoP; T = TP; }
    else                 { xg = xgQ; WP = WQ2; ho = hoQ; T = TQ; }

    const float* xgd = xg + (size_t)dir * BB * T * GATES;

    // B fragments (Whh bf16x2): constant across steps. 32 short8 = 128 VGPR.
    short8_t Bf[4][4][2];
#pragma unroll
    for (int g = 0; g < 4; ++g)
#pragma unroll
        for (int k0 = 0; k0 < 4; ++k0)
#pragma unroll
            for (int pl = 0; pl < 2; ++pl) {
                const ushort* src = WP + (size_t)pl * 1024 * 128 +
                    (size_t)(dir * 512 + g * 128 + col) * 128 + k0 * 32 + (l >> 4) * 8;
                Bf[g][k0][pl] = *reinterpret_cast<const short8_t*>(src);
            }

    // A buffers: [buf][plane][k0][lane*8] bf16, 16 KB total.
    __shared__ __align__(16) ushort Ah[2][2][4][64 * 8];

    // zero buf 0 (h(-1) = 0): 512 threads x 16B = 8 KB
    {
        int pl = tid >> 8, k0 = (tid >> 6) & 3, slot = tid & 63;
        *reinterpret_cast<int4*>(&Ah[0][pl][k0][slot * 8]) = make_int4(0, 0, 0, 0);
    }

    float cc[4] = {0.f, 0.f, 0.f, 0.f};

    int t = dir ? (T - 1) : 0;
    const int dt = dir ? -1 : 1;

    // scatter-write constants for this lane
    const int k0w = w >> 1;                       // col's k0 group
    const int lg  = ((l & 15) >> 3) + (w & 1) * 2; // col's lane-group
    const int el  = col & 7;

    float xc[4][4], xn[4][4];
#pragma unroll
    for (int g = 0; g < 4; ++g)
#pragma unroll
        for (int r = 0; r < 4; ++r)
            xc[g][r] = xgd[((size_t)(cg + rb + r) * T + t) * GATES + g * 128 + col];

    __syncthreads();

    for (int step = 0; step < T; ++step) {
        const int tn = t + dt;
        const int rbuf = step & 1, wbuf = rbuf ^ 1;

        // prefetch next step's xg (hidden under this step's compute)
        if (step + 1 < T) {
#pragma unroll
            for (int g = 0; g < 4; ++g)
#pragma unroll
                for (int r = 0; r < 4; ++r)
                    xn[g][r] = xgd[((size_t)(cg + rb + r) * T + tn) * GATES + g * 128 + col];
        }

        // A fragments (h bf16x2) for this step
        short8_t Af[4][2];
#pragma unroll
        for (int k0 = 0; k0 < 4; ++k0) {
            Af[k0][0] = *reinterpret_cast<const short8_t*>(&Ah[rbuf][0][k0][l * 8]);
            Af[k0][1] = *reinterpret_cast<const short8_t*>(&Ah[rbuf][1][k0][l * 8]);
        }

        f32x4 acc[4];
#pragma unroll
        for (int g = 0; g < 4; ++g) acc[g] = (f32x4)0.f;
#pragma unroll
        for (int k0 = 0; k0 < 4; ++k0) {
#pragma unroll
            for (int g = 0; g < 4; ++g) {
                f32x4 a = acc[g];
                a = __builtin_amdgcn_mfma_f32_16x16x32_bf16(Af[k0][0], Bf[g][k0][0], a, 0, 0, 0);
                a = __builtin_amdgcn_mfma_f32_16x16x32_bf16(Af[k0][0], Bf[g][k0][1], a, 0, 0, 0);
                a = __builtin_amdgcn_mfma_f32_16x16x32_bf16(Af[k0][1], Bf[g][k0][0], a, 0, 0, 0);
                a = __builtin_amdgcn_mfma_f32_16x16x32_bf16(Af[k0][1], Bf[g][k0][1], a, 0, 0, 0);
                acc[g] = a;
            }
        }

        // in-lane cell update for 4 chains; split h -> 2 bf16 planes; scatter
#pragma unroll
        for (int r = 0; r < 4; ++r) {
            float pi = acc[0][r] + xc[0][r];
            float pf = acc[1][r] + xc[1][r];
            float pg = acc[2][r] + xc[2][r];
            float po = acc[3][r] + xc[3][r];
            float ig = fast_sigmoid(pi);
            float fg = fast_sigmoid(pf);
            float gg = fast_tanh(pg);
            float og = fast_sigmoid(po);
            cc[r] = fg * cc[r] + ig * gg;
            float h = og * fast_tanh(cc[r]);

            uint32_t hb = __float_as_uint(h);
            uint32_t u1 = hb & 0xffff0000u;
            float r1 = h - __uint_as_float(u1);
            uint32_t u2 = __float_as_uint(r1) & 0xffff0000u;

            int slot = (rb + r + lg * 16) * 8 + el;
            Ah[wbuf][0][k0w][slot] = (ushort)(u1 >> 16);
            Ah[wbuf][1][k0w][slot] = (ushort)(u2 >> 16);

            ho[((size_t)(cg + rb + r) * T + t) * 256 + dir * HD + col] = h;
        }
        __syncthreads();

#pragma unroll
        for (int g = 0; g < 4; ++g)
#pragma unroll
            for (int r = 0; r < 4; ++r) xc[g][r] = xn[g][r];
        t = tn;
    }
}

// ---------------------------------------------------------------------------
__global__ void rowdot(const float* __restrict__ X, const float* __restrict__ w,
                       float* __restrict__ out, int N, int D)
{
    int gw   = (int)((blockIdx.x * blockDim.x + threadIdx.x) >> 6);
    int lane = threadIdx.x & 63;
    if (gw >= N) return;
    const float* xp = X + (size_t)gw * D;
    float s = 0.f;
    for (int d = lane; d < D; d += 64) s += xp[d] * w[d];
#pragma unroll
    for (int off = 32; off; off >>= 1) s += __shfl_down(s, off);
    if (lane == 0) out[gw] = s;
}

// ---------------------------------------------------------------------------
__global__ __launch_bounds__(256)
void att_s(const float* __restrict__ co, const float* __restrict__ qo,
           const float* __restrict__ cw, const float* __restrict__ qw,
           const float* __restrict__ wcq, const float* __restrict__ attb,
           float* __restrict__ s)
{
    int b  = blockIdx.x;
    int c0 = blockIdx.y * 64;
    int tid = threadIdx.x;
    int tq = tid & 15, trc = tid >> 4;
    int cbase = c0 + trc * 4, qbase = tq * 4;

    float acc[4][4];
#pragma unroll
    for (int i = 0; i < 4; ++i)
#pragma unroll
        for (int j = 0; j < 4; ++j) acc[i][j] = 0.f;

    for (int d = 0; d < 256; d += 4) {
        float4 wv = *(const float4*)&wcq[d];
        float4 cv[4], qv[4];
#pragma unroll
        for (int i = 0; i < 4; ++i) {
            float4 v = *(const float4*)&co[((size_t)b * CL + cbase + i) * 256 + d];
            cv[i].x = v.x * wv.x; cv[i].y = v.y * wv.y;
            cv[i].z = v.z * wv.z; cv[i].w = v.w * wv.w;
        }
#pragma unroll
        for (int j = 0; j < 4; ++j)
            qv[j] = *(const float4*)&qo[((size_t)b * QL + qbase + j) * 256 + d];
#pragma unroll
        for (int i = 0; i < 4; ++i)
#pragma unroll
            for (int j = 0; j < 4; ++j)
                acc[i][j] += cv[i].x * qv[j].x + cv[i].y * qv[j].y +
                             cv[i].z * qv[j].z + cv[i].w * qv[j].w;
    }
    float ab = attb[0];
#pragma unroll
    for (int i = 0; i < 4; ++i) {
        float cwv = cw[b * CL + cbase + i];
#pragma unroll
        for (int j = 0; j < 4; ++j) {
            s[((size_t)b * CL + cbase + i) * QL + qbase + j] =
                acc[i][j] + cwv + qw[b * QL + qbase + j] + ab;
        }
    }
}

// ---------------------------------------------------------------------------
__global__ void softmax_q(float* __restrict__ s, float* __restrict__ smax)
{
    int gw   = (int)((blockIdx.x * blockDim.x + threadIdx.x) >> 6);
    int lane = threadIdx.x & 63;
    float v = s[(size_t)gw * QL + lane];
    float mx = v;
#pragma unroll
    for (int off = 32; off; off >>= 1) mx = fmaxf(mx, __shfl_xor(mx, off));
    float e = expf(v - mx);
    float sm = e;
#pragma unroll
    for (int off = 32; off; off >>= 1) sm += __shfl_xor(sm, off);
    s[(size_t)gw * QL + lane] = e / sm;
    if (lane == 0) smax[gw] = mx;
}

// ---------------------------------------------------------------------------
__global__ __launch_bounds__(512)
void bw_k(const float* __restrict__ smax, float* __restrict__ bw)
{
    int b = blockIdx.x, c = threadIdx.x;
    int lane = c & 63, wid = c >> 6;
    __shared__ float red[8];
    float v = smax[b * CL + c];
    float mx = v;
#pragma unroll
    for (int off = 32; off; off >>= 1) mx = fmaxf(mx, __shfl_xor(mx, off));
    if (lane == 0) red[wid] = mx;
    __syncthreads();
    float bm = red[0];
#pragma unroll
    for (int w = 1; w < 8; ++w) bm = fmaxf(bm, red[w]);
    float e = expf(v - bm);
    float sm = e;
#pragma unroll
    for (int off = 32; off; off >>= 1) sm += __shfl_xor(sm, off);
    __syncthreads();
    if (lane == 0) red[wid] = sm;
    __syncthreads();
    float ts = 0.f;
#pragma unroll
    for (int w = 0; w < 8; ++w) ts += red[w];
    bw[b * CL + c] = e / ts;
}

// ---------------------------------------------------------------------------
__global__ __launch_bounds__(256)
void q2c_k(const float* __restrict__ bw, const float* __restrict__ co,
           float* __restrict__ q2c)
{
    int b = blockIdx.x, d = threadIdx.x;
    float acc = 0.f;
    for (int c = 0; c < CL; ++c)
        acc += bw[b * CL + c] * co[((size_t)b * CL + c) * 256 + d];
    q2c[b * 256 + d] = acc;
}

// ---------------------------------------------------------------------------
__global__ __launch_bounds__(256)
void c2q_g(const float* __restrict__ a, const float* __restrict__ qo,
           const float* __restrict__ co, const float* __restrict__ q2c,
           float* __restrict__ g)
{
    int b  = blockIdx.x;
    int c  = blockIdx.y * 64 + (threadIdx.x >> 2);
    int gq = threadIdx.x & 3;

    float4 acc[16];
#pragma unroll
    for (int jj = 0; jj < 16; ++jj) acc[jj] = make_float4(0.f, 0.f, 0.f, 0.f);

    const float* ar = a + ((size_t)b * CL + c) * QL;
    for (int q = 0; q < QL; ++q) {
        float av = ar[q];
        const float* qr = qo + ((size_t)b * QL + q) * 256;
#pragma unroll
        for (int jj = 0; jj < 16; ++jj) {
            float4 qv = *(const float4*)&qr[4 * gq + 16 * jj];
            acc[jj].x += av * qv.x; acc[jj].y += av * qv.y;
            acc[jj].z += av * qv.z; acc[jj].w += av * qv.w;
        }
    }
    size_t gbase = ((size_t)b * CL + c) * 1024;
    const float* corow = co + ((size_t)b * CL + c) * 256;
    const float* q2cr  = q2c + b * 256;
#pragma unroll
    for (int jj = 0; jj < 16; ++jj) {
        int d = 4 * gq + 16 * jj;
        float4 cv = *(const float4*)&corow[d];
        float4 qc = *(const float4*)&q2cr[d];
        float4 cq = acc[jj];
        *(float4*)&g[gbase + d] = cv;
        *(float4*)&g[gbase + 256 + d] = cq;
        float4 t;
        t.x = cv.x * cq.x; t.y = cv.y * cq.y; t.z = cv.z * cq.z; t.w = cv.w * cq.w;
        *(float4*)&g[gbase + 512 + d] = t;
        t.x = cv.x * qc.x; t.y = cv.y * qc.y; t.z = cv.z * qc.z; t.w = cv.w * qc.w;
        *(float4*)&g[gbase + 768 + d] = t;
    }
}

// ---------------------------------------------------------------------------
__global__ void logits_k(const float* __restrict__ g, const float* __restrict__ m,
                         const float* __restrict__ m2o,
                         const float* __restrict__ p1wg, const float* __restrict__ p1wm,
                         const float* __restrict__ p1b,
                         const float* __restrict__ p2wg, const float* __restrict__ p2wm,
                         const float* __restrict__ p2b,
                         float* __restrict__ lp1, float* __restrict__ lp2)
{
    int row  = (int)((blockIdx.x * blockDim.x + threadIdx.x) >> 6);
    int lane = threadIdx.x & 63;
    const float* gr = g + (size_t)row * 1024;
    float s1 = 0.f, s2 = 0.f;
    for (int d = lane; d < 1024; d += 64) {
        float gv = gr[d];
        s1 += gv * p1wg[d];
        s2 += gv * p2wg[d];
    }
    const float* mr  = m   + (size_t)row * 256;
    const float* m2r = m2o + (size_t)row * 256;
    for (int d = lane; d < 256; d += 64) {
        s1 += mr[d] * p1wm[d];
        s2 += m2r[d] * p2wm[d];
    }
#pragma unroll
    for (int off = 32; off; off >>= 1) {
        s1 += __shfl_down(s1, off);
        s2 += __shfl_down(s2, off);
    }
    if (lane == 0) {
        lp1[row] = s1 + p1b[0];
        lp2[row] = s2 + p2b[0];
    }
}

// ---------------------------------------------------------------------------
__global__ __launch_bounds__(512)
void masked_softmax(const float* __restrict__ lp1, const float* __restrict__ lp2,
                    const int* __restrict__ p, float* __restrict__ out)
{
    int b = blockIdx.x, c = threadIdx.x;
    int lane = c & 63, wid = c >> 6;
    const float* lp = blockIdx.y ? lp2 : lp1;
    float* o = out + (size_t)blockIdx.y * BB * CL;

    __shared__ float red[8];
    float v = (p[b * CL + c] != 0) ? lp[b * CL + c] : -INFINITY;
    float mx = v;
#pragma unroll
    for (int off = 32; off; off >>= 1) mx = fmaxf(mx, __shfl_xor(mx, off));
    if (lane == 0) red[wid] = mx;
    __syncthreads();
    float bm = red[0];
#pragma unroll
    for (int w = 1; w < 8; ++w) bm = fmaxf(bm, red[w]);
    float e = expf(v - bm);
    float sm = e;
#pragma unroll
    for (int off = 32; off; off >>= 1) sm += __shfl_xor(sm, off);
    __syncthreads();
    if (lane == 0) red[wid] = sm;
    __syncthreads();
    float ts = 0.f;
#pragma unroll
    for (int w = 0; w < 8; ++w) ts += red[w];
    o[b * CL + c] = e / ts;
}

// ---------------------------------------------------------------------------
extern "C" void kernel_launch(void* const* d_in, const int* in_sizes, int n_in,
                              void* d_out, int out_size, void* d_ws, size_t ws_size,
                              hipStream_t stream)
{
    const int*   p        = (const int*)d_in[0];
    const int*   q        = (const int*)d_in[1];
    const float* emb      = (const float*)d_in[2];
    const float* qenc_Wih = (const float*)d_in[3];
    const float* qenc_Whh = (const float*)d_in[4];
    const float* qenc_b   = (const float*)d_in[5];
    const float* penc_Wih = (const float*)d_in[6];
    const float* penc_Whh = (const float*)d_in[7];
    const float* penc_b   = (const float*)d_in[8];
    const float* m1_Wih   = (const float*)d_in[9];
    const float* m1_Whh   = (const float*)d_in[10];
    const float* m1_b     = (const float*)d_in[11];
    const float* m2_Wih   = (const float*)d_in[12];
    const float* m2_Whh   = (const float*)d_in[13];
    const float* m2_b     = (const float*)d_in[14];
    const float* out_Wih  = (const float*)d_in[15];
    const float* out_Whh  = (const float*)d_in[16];
    const float* out_b    = (const float*)d_in[17];
    const float* att_wc   = (const float*)d_in[18];
    const float* att_wq   = (const float*)d_in[19];
    const float* att_wcq  = (const float*)d_in[20];
    const float* att_b    = (const float*)d_in[21];
    const float* p1_wg    = (const float*)d_in[22];
    const float* p1_wm    = (const float*)d_in[23];
    const float* p1_b     = (const float*)d_in[24];
    const float* p2_wg    = (const float*)d_in[25];
    const float* p2_wm    = (const float*)d_in[26];
    const float* p2_b     = (const float*)d_in[27];

    float* ws = (float*)d_ws;
    size_t off = 0;
    auto alloc = [&](size_t n) { float* r = ws + off; off += n; return r; };
    auto allocU = [&](size_t nsh) { ushort* r = (ushort*)(ws + off); off += (nsh + 1) / 2; return r; };

    const size_t NC = (size_t)BB * CL;     // 32768
    const size_t NQ = (size_t)BB * QL;     // 4096

    float* xgA  = alloc(2 * NC * GATES);   // gate preacts, reused per layer
    float* gbuf = alloc(NC * 1024);        // g  (xgQ aliases its head: dead before g written)
    float* xgQ  = gbuf;
    float* co   = alloc(NC * 256);
    float* qo   = alloc(NQ * 256);
    float* sbuf = alloc(NC * QL);          // s, then a (in place)
    float* cw   = alloc(NC);
    float* qw   = alloc(NQ);
    float* smax = alloc(NC);
    float* bw   = alloc(NC);
    float* q2c  = alloc((size_t)BB * 256);
    float* mmid = alloc(NC * 256);
    float* mbuf = alloc(NC * 256);
    float* m2o  = alloc(NC * 256);
    float* lp1  = alloc(NC);
    float* lp2  = alloc(NC);
    // bf16 weight planes: Wih [3][1024][Ksp]
    ushort* WqP  = allocU((size_t)3 * 1024 * 320);
    ushort* WpP  = allocU((size_t)3 * 1024 * 320);
    ushort* Wm1P = allocU((size_t)3 * 1024 * 1024);
    ushort* Wm2P = allocU((size_t)3 * 1024 * 256);
    ushort* WoP  = allocU((size_t)3 * 1024 * 256);
    // Whh planes (Ksp=128); scan uses planes 0,1
    ushort* WqH  = allocU((size_t)3 * 1024 * 128);
    ushort* WpH  = allocU((size_t)3 * 1024 * 128);
    ushort* Wm1H = allocU((size_t)3 * 1024 * 128);
    ushort* Wm2H = allocU((size_t)3 * 1024 * 128);
    ushort* WoH  = allocU((size_t)3 * 1024 * 128);
    (void)ws_size; (void)in_sizes; (void)n_in; (void)out_size;

    // ---- weight splits ----
    splitW_k<<<dim3(1024 * 80 / 256), 256, 0, stream>>>(qenc_Wih, WqP, 300, 320);
    splitW_k<<<dim3(1024 * 80 / 256), 256, 0, stream>>>(penc_Wih, WpP, 300, 320);
    splitW_k<<<dim3(1024 * 256 / 256), 256, 0, stream>>>(m1_Wih, Wm1P, 1024, 1024);
    splitW_k<<<dim3(1024 * 64 / 256), 256, 0, stream>>>(m2_Wih, Wm2P, 256, 256);
    splitW_k<<<dim3(1024 * 64 / 256), 256, 0, stream>>>(out_Wih, WoP, 256, 256);
    splitW_k<<<dim3(1024 * 32 / 256), 256, 0, stream>>>(qenc_Whh, WqH, 128, 128);
    splitW_k<<<dim3(1024 * 32 / 256), 256, 0, stream>>>(penc_Whh, WpH, 128, 128);
    splitW_k<<<dim3(1024 * 32 / 256), 256, 0, stream>>>(m1_Whh, Wm1H, 128, 128);
    splitW_k<<<dim3(1024 * 32 / 256), 256, 0, stream>>>(m2_Whh, Wm2H, 128, 128);
    splitW_k<<<dim3(1024 * 32 / 256), 256, 0, stream>>>(out_Whh, WoH, 128, 128);

    // ---- encoders (P and Q scans in one launch via z) ----
    gemm_bf16x3<<<dim3((int)(NQ / TM), 4, 2), 256, 0, stream>>>(emb, q, WqP, qenc_b, xgQ, (int)NQ, 300, 320);
    gemm_bf16x3<<<dim3((int)(NC / TM), 4, 2), 256, 0, stream>>>(emb, p, WpP, penc_b, xgA, (int)NC, 300, 320);
    lstm_mfma<<<dim3(4, 2, 2), 512, 0, stream>>>(xgA, WpH, co, CL,
                                                 xgQ, WqH, qo, QL);

    // ---- attention ----
    rowdot<<<dim3((int)(NC * 64 / 256)), 256, 0, stream>>>(co, att_wc, cw, (int)NC, 256);
    rowdot<<<dim3((int)(NQ * 64 / 256)), 256, 0, stream>>>(qo, att_wq, qw, (int)NQ, 256);
    att_s<<<dim3(BB, CL / 64), 256, 0, stream>>>(co, qo, cw, qw, att_wcq, att_b, sbuf);
    softmax_q<<<dim3((int)(NC * 64 / 256)), 256, 0, stream>>>(sbuf, smax);
    bw_k<<<dim3(BB), 512, 0, stream>>>(smax, bw);
    q2c_k<<<dim3(BB), 256, 0, stream>>>(bw, co, q2c);
    c2q_g<<<dim3(BB, CL / 64), 256, 0, stream>>>(sbuf, qo, co, q2c, gbuf);

    // ---- modeling layers ----
    gemm_bf16x3<<<dim3((int)(NC / TM), 4, 2), 256, 0, stream>>>(gbuf, nullptr, Wm1P, m1_b, xgA, (int)NC, 1024, 1024);
    lstm_mfma<<<dim3(4, 2, 1), 512, 0, stream>>>(xgA, Wm1H, mmid, CL,
                                                 xgA, Wm1H, mmid, CL);
    gemm_bf16x3<<<dim3((int)(NC / TM), 4, 2), 256, 0, stream>>>(mmid, nullptr, Wm2P, m2_b, xgA, (int)NC, 256, 256);
    lstm_mfma<<<dim3(4, 2, 1), 512, 0, stream>>>(xgA, Wm2H, mbuf, CL,
                                                 xgA, Wm2H, mbuf, CL);
    gemm_bf16x3<<<dim3((int)(NC / TM), 4, 2), 256, 0, stream>>>(mbuf, nullptr, WoP, out_b, xgA, (int)NC, 256, 256);
    lstm_mfma<<<dim3(4, 2, 1), 512, 0, stream>>>(xgA, WoH, m2o, CL,
                                                 xgA, WoH, m2o, CL);

    // ---- output ----
    logits_k<<<dim3((int)(NC * 64 / 256)), 256, 0, stream>>>(gbuf, mbuf, m2o,
        p1_wg, p1_wm, p1_b, p2_wg, p2_wm, p2_b, lp1, lp2);
    masked_softmax<<<dim3(BB, 2), 512, 0, stream>>>(lp1, lp2, p, (float*)d_out);
}

// Round 6
// 4968.650 us; speedup vs baseline: 1.0096x; 1.0096x over previous
//
#include <hip/hip_runtime.h>
#include <math.h>
#include <stdint.h>

#define HD    128      // hidden
#define GATES 512      // 4H
#define BB    64       // batch
#define CL    512      // context len
#define QL    64       // query len

#define TM 128
#define TN 128
#define TK 32

typedef __attribute__((ext_vector_type(8))) short short8_t;
typedef __attribute__((ext_vector_type(4))) short short4_t;
typedef __attribute__((ext_vector_type(4))) float f32x4;

__device__ __forceinline__ float fast_sigmoid(float x) {
    float e = __builtin_amdgcn_exp2f(-1.44269504f * x);
    return __builtin_amdgcn_rcpf(1.f + e);
}
__device__ __forceinline__ float fast_tanh(float x) {
    float e = __builtin_amdgcn_exp2f(2.88539008f * x);
    float r = __builtin_amdgcn_rcpf(e + 1.f);
    return 1.f - 2.f * r;
}

// ---------------------------------------------------------------------------
// Split W (rows=1024, K) fp32 into 3 bf16 planes, each (1024, Ksp), padded.
// ---------------------------------------------------------------------------
__global__ __launch_bounds__(256)
void splitW_k(const float* __restrict__ W, ushort* __restrict__ P, int K, int Ksp)
{
    int idx = blockIdx.x * 256 + threadIdx.x;
    int per_row = Ksp >> 2;
    int total = 1024 * per_row;
    if (idx >= total) return;
    int row = idx / per_row;
    int c4  = (idx - row * per_row) * 4;

    short4_t o1, o2, o3;
#pragma unroll
    for (int e = 0; e < 4; ++e) {
        int k = c4 + e;
        float x = (k < K) ? W[(size_t)row * K + k] : 0.f;
        uint32_t u1 = __float_as_uint(x) & 0xffff0000u;
        float r1 = x - __uint_as_float(u1);
        uint32_t u2 = __float_as_uint(r1) & 0xffff0000u;
        float r2 = r1 - __uint_as_float(u2);
        uint32_t u3 = __float_as_uint(r2) & 0xffff0000u;
        o1[e] = (short)(u1 >> 16);
        o2[e] = (short)(u2 >> 16);
        o3[e] = (short)(u3 >> 16);
    }
    size_t base = (size_t)row * Ksp + c4;
    size_t ps = (size_t)1024 * Ksp;
    *reinterpret_cast<short4_t*>(&P[base]) = o1;
    *reinterpret_cast<short4_t*>(&P[ps + base]) = o2;
    *reinterpret_cast<short4_t*>(&P[2 * ps + base]) = o3;
}

// ---------------------------------------------------------------------------
// MFMA GEMM, bf16x3 split (6 cross-term MFMAs per k-tile).
// ---------------------------------------------------------------------------
__global__ __launch_bounds__(256)
void gemm_bf16x3(const float* __restrict__ A, const int* __restrict__ gidx,
                 const ushort* __restrict__ Wpl, const float* __restrict__ bias,
                 float* __restrict__ C, int M, int K, int Ksp)
{
    const int dir  = blockIdx.z;
    const int m0   = blockIdx.x * TM;
    const int n0   = blockIdx.y * TN;
    const int tid  = threadIdx.x;
    const int lane = tid & 63;
    const int wid  = tid >> 6;
    const int wm   = (wid >> 1) * 64;
    const int wn   = (wid & 1) * 64;

    __shared__ __align__(16) ushort As[3][TM * TK];
    __shared__ __align__(16) ushort Bs[3][TN * TK];

    const int ar = tid >> 3;
    const int ac = (tid & 7) * 4;

    size_t arow[4];
#pragma unroll
    for (int r = 0; r < 4; ++r) {
        int m = m0 + ar + r * 32;
        arow[r] = gidx ? (size_t)gidx[m] : (size_t)m;
    }

    f32x4 acc[4][4];
#pragma unroll
    for (int i = 0; i < 4; ++i)
#pragma unroll
        for (int j = 0; j < 4; ++j) acc[i][j] = (f32x4)0.f;

    const size_t wps    = (size_t)1024 * Ksp;
    const size_t wdbase = (size_t)dir * 512 * Ksp;

    for (int k0 = 0; k0 < Ksp; k0 += TK) {
#pragma unroll
        for (int r = 0; r < 4; ++r) {
            float4 v = make_float4(0.f, 0.f, 0.f, 0.f);
            if (k0 + ac < K) v = *(const float4*)(A + arow[r] * K + k0 + ac);
            float xs[4] = {v.x, v.y, v.z, v.w};
            short4_t o1, o2, o3;
#pragma unroll
            for (int e = 0; e < 4; ++e) {
                uint32_t u1 = __float_as_uint(xs[e]) & 0xffff0000u;
                float r1 = xs[e] - __uint_as_float(u1);
                uint32_t u2 = __float_as_uint(r1) & 0xffff0000u;
                float r2 = r1 - __uint_as_float(u2);
                uint32_t u3 = __float_as_uint(r2) & 0xffff0000u;
                o1[e] = (short)(u1 >> 16);
                o2[e] = (short)(u2 >> 16);
                o3[e] = (short)(u3 >> 16);
            }
            int wb = (ar + r * 32) * TK + ac;
            *reinterpret_cast<short4_t*>(&As[0][wb]) = o1;
            *reinterpret_cast<short4_t*>(&As[1][wb]) = o2;
            *reinterpret_cast<short4_t*>(&As[2][wb]) = o3;
        }
#pragma unroll
        for (int t = 0; t < 6; ++t) {
            int chunk = wid * 6 + t;
            int pl = chunk >> 3;
            int ch = chunk & 7;
            int rrow = ch * 16 + (lane >> 2);
            const ushort* src = Wpl + (size_t)pl * wps + wdbase +
                                (size_t)(n0 + rrow) * Ksp + k0 + (lane & 3) * 8;
            ushort* dst = &Bs[pl][ch * 512];
            __builtin_amdgcn_global_load_lds(
                reinterpret_cast<const __attribute__((address_space(1))) void*>(
                    reinterpret_cast<uintptr_t>(src)),
                reinterpret_cast<__attribute__((address_space(3))) void*>(
                    reinterpret_cast<uintptr_t>(dst)),
                16, 0, 0);
        }
        __syncthreads();

        const int koff = (lane >> 4) * 8;
        short8_t bf0[4], bf1[4], bf2[4];
#pragma unroll
        for (int j = 0; j < 4; ++j) {
            int nrow = wn + j * 16 + (lane & 15);
            bf0[j] = *reinterpret_cast<const short8_t*>(&Bs[0][nrow * TK + koff]);
            bf1[j] = *reinterpret_cast<const short8_t*>(&Bs[1][nrow * TK + koff]);
            bf2[j] = *reinterpret_cast<const short8_t*>(&Bs[2][nrow * TK + koff]);
        }
#pragma unroll
        for (int i = 0; i < 4; ++i) {
            int mrow = wm + i * 16 + (lane & 15);
            short8_t a1 = *reinterpret_cast<const short8_t*>(&As[0][mrow * TK + koff]);
            short8_t a2 = *reinterpret_cast<const short8_t*>(&As[1][mrow * TK + koff]);
            short8_t a3 = *reinterpret_cast<const short8_t*>(&As[2][mrow * TK + koff]);
#pragma unroll
            for (int j = 0; j < 4; ++j) {
                f32x4 c = acc[i][j];
                c = __builtin_amdgcn_mfma_f32_16x16x32_bf16(a1, bf0[j], c, 0, 0, 0);
                c = __builtin_amdgcn_mfma_f32_16x16x32_bf16(a1, bf1[j], c, 0, 0, 0);
                c = __builtin_amdgcn_mfma_f32_16x16x32_bf16(a2, bf0[j], c, 0, 0, 0);
                c = __builtin_amdgcn_mfma_f32_16x16x32_bf16(a2, bf1[j], c, 0, 0, 0);
                c = __builtin_amdgcn_mfma_f32_16x16x32_bf16(a1, bf2[j], c, 0, 0, 0);
                c = __builtin_amdgcn_mfma_f32_16x16x32_bf16(a3, bf0[j], c, 0, 0, 0);
                acc[i][j] = c;
            }
        }
        __syncthreads();
    }

    float* Cd = C + (size_t)dir * M * 512;
#pragma unroll
    for (int j = 0; j < 4; ++j) {
        int col = n0 + wn + j * 16 + (lane & 15);
        float bv = bias[dir * 512 + col];
#pragma unroll
        for (int i = 0; i < 4; ++i) {
            int rbase = m0 + wm + i * 16 + ((lane >> 4) << 2);
#pragma unroll
            for (int r = 0; r < 4; ++r)
                Cd[(size_t)(rbase + r) * 512 + col] = acc[i][j][r] + bv;
        }
    }
}

// ---------------------------------------------------------------------------
// LSTM scan v5: block per (batch, dir[, layer via z]); 256 threads (4 waves).
// Thread j owns gate rows j and j+256: (i_u, g_u) for j=u<128, (f_u, o_u) for
// j=u+128. Each ds_read_b128 h-broadcast feeds 8 FMAs (2 gates). Update
// exchange is ONE float per unit: thread u writes ig = sig(i)*tanh(g);
// thread u+128 (holds c) reads it: c = sig(f)*c + ig, h = sig(o)*tanh(c).
// ---------------------------------------------------------------------------
__global__ __launch_bounds__(256, 1)
void lstm_scan5(const float* __restrict__ xgP, const float* __restrict__ WhhP,
                float* __restrict__ hoP, int TP,
                const float* __restrict__ xgQ, const float* __restrict__ WhhQ,
                float* __restrict__ hoQ, int TQ)
{
    const int b   = blockIdx.x;
    const int dir = blockIdx.y;
    const int j   = threadIdx.x;        // 0..255
    const int u   = j & 127;

    const float* xg; const float* Whh; float* ho; int T;
    if (blockIdx.z == 0) { xg = xgP; Whh = WhhP; ho = hoP; T = TP; }
    else                 { xg = xgQ; Whh = WhhQ; ho = hoQ; T = TQ; }

    const float* xgd = xg + (size_t)dir * BB * T * GATES;
    const float* wrA = Whh + ((size_t)dir * GATES + j) * HD;
    const float* wrB = Whh + ((size_t)dir * GATES + j + 256) * HD;

    float4 wA[32], wB[32];
#pragma unroll
    for (int kk = 0; kk < 32; ++kk) {
        wA[kk] = *(const float4*)(wrA + kk * 4);
        wB[kk] = *(const float4*)(wrB + kk * 4);
    }

    __shared__ __align__(16) float hs[HD];
    __shared__ float igb[HD];

    if (j < HD) hs[j] = 0.f;
    float c = 0.f;
    __syncthreads();

    int t = dir ? (T - 1) : 0;
    const int dt = dir ? -1 : 1;

    float xA = xgd[((size_t)b * T + t) * GATES + j];
    float xB = xgd[((size_t)b * T + t) * GATES + j + 256];

    for (int step = 0; step < T; ++step) {
        const int tn = t + dt;
        float xAn = 0.f, xBn = 0.f;
        if (step + 1 < T) {
            xAn = xgd[((size_t)b * T + tn) * GATES + j];
            xBn = xgd[((size_t)b * T + tn) * GATES + j + 256];
        }

        float a0 = xA, a1 = 0.f, a2 = 0.f, a3 = 0.f;
        float b0 = xB, b1 = 0.f, b2 = 0.f, b3 = 0.f;
#pragma unroll
        for (int kk = 0; kk < 32; ++kk) {
            float4 h4 = *(const float4*)&hs[kk * 4];
            float4 wa = wA[kk], wb = wB[kk];
            switch (kk & 3) {
            case 0: a0 += wa.x*h4.x + wa.y*h4.y + wa.z*h4.z + wa.w*h4.w;
                    b0 += wb.x*h4.x + wb.y*h4.y + wb.z*h4.z + wb.w*h4.w; break;
            case 1: a1 += wa.x*h4.x + wa.y*h4.y + wa.z*h4.z + wa.w*h4.w;
                    b1 += wb.x*h4.x + wb.y*h4.y + wb.z*h4.z + wb.w*h4.w; break;
            case 2: a2 += wa.x*h4.x + wa.y*h4.y + wa.z*h4.z + wa.w*h4.w;
                    b2 += wb.x*h4.x + wb.y*h4.y + wb.z*h4.z + wb.w*h4.w; break;
            default:a3 += wa.x*h4.x + wa.y*h4.y + wa.z*h4.z + wa.w*h4.w;
                    b3 += wb.x*h4.x + wb.y*h4.y + wb.z*h4.z + wb.w*h4.w; break;
            }
        }
        float preA = (a0 + a1) + (a2 + a3);
        float preB = (b0 + b1) + (b2 + b3);

        if (j < HD) {
            // preA = i-gate, preB = g-gate
            igb[u] = fast_sigmoid(preA) * fast_tanh(preB);
        }
        __syncthreads();
        if (j >= HD) {
            // preA = f-gate, preB = o-gate
            float fg = fast_sigmoid(preA);
            float og = fast_sigmoid(preB);
            c = fg * c + igb[u];
            float h = og * fast_tanh(c);
            hs[u] = h;
            ho[((size_t)b * T + t) * 256 + dir * HD + u] = h;
        }
        __syncthreads();
        xA = xAn; xB = xBn;
        t = tn;
    }
}

// ---------------------------------------------------------------------------
__global__ void rowdot(const float* __restrict__ X, const float* __restrict__ w,
                       float* __restrict__ out, int N, int D)
{
    int gw   = (int)((blockIdx.x * blockDim.x + threadIdx.x) >> 6);
    int lane = threadIdx.x & 63;
    if (gw >= N) return;
    const float* xp = X + (size_t)gw * D;
    float s = 0.f;
    for (int d = lane; d < D; d += 64) s += xp[d] * w[d];
#pragma unroll
    for (int off = 32; off; off >>= 1) s += __shfl_down(s, off);
    if (lane == 0) out[gw] = s;
}

// ---------------------------------------------------------------------------
__global__ __launch_bounds__(256)
void att_s(const float* __restrict__ co, const float* __restrict__ qo,
           const float* __restrict__ cw, const float* __restrict__ qw,
           const float* __restrict__ wcq, const float* __restrict__ attb,
           float* __restrict__ s)
{
    int b  = blockIdx.x;
    int c0 = blockIdx.y * 64;
    int tid = threadIdx.x;
    int tq = tid & 15, trc = tid >> 4;
    int cbase = c0 + trc * 4, qbase = tq * 4;

    float acc[4][4];
#pragma unroll
    for (int i = 0; i < 4; ++i)
#pragma unroll
        for (int j = 0; j < 4; ++j) acc[i][j] = 0.f;

    for (int d = 0; d < 256; d += 4) {
        float4 wv = *(const float4*)&wcq[d];
        float4 cv[4], qv[4];
#pragma unroll
        for (int i = 0; i < 4; ++i) {
            float4 v = *(const float4*)&co[((size_t)b * CL + cbase + i) * 256 + d];
            cv[i].x = v.x * wv.x; cv[i].y = v.y * wv.y;
            cv[i].z = v.z * wv.z; cv[i].w = v.w * wv.w;
        }
#pragma unroll
        for (int j = 0; j < 4; ++j)
            qv[j] = *(const float4*)&qo[((size_t)b * QL + qbase + j) * 256 + d];
#pragma unroll
        for (int i = 0; i < 4; ++i)
#pragma unroll
            for (int j = 0; j < 4; ++j)
                acc[i][j] += cv[i].x * qv[j].x + cv[i].y * qv[j].y +
                             cv[i].z * qv[j].z + cv[i].w * qv[j].w;
    }
    float ab = attb[0];
#pragma unroll
    for (int i = 0; i < 4; ++i) {
        float cwv = cw[b * CL + cbase + i];
#pragma unroll
        for (int j = 0; j < 4; ++j) {
            s[((size_t)b * CL + cbase + i) * QL + qbase + j] =
                acc[i][j] + cwv + qw[b * QL + qbase + j] + ab;
        }
    }
}

// ---------------------------------------------------------------------------
__global__ void softmax_q(float* __restrict__ s, float* __restrict__ smax)
{
    int gw   = (int)((blockIdx.x * blockDim.x + threadIdx.x) >> 6);
    int lane = threadIdx.x & 63;
    float v = s[(size_t)gw * QL + lane];
    float mx = v;
#pragma unroll
    for (int off = 32; off; off >>= 1) mx = fmaxf(mx, __shfl_xor(mx, off));
    float e = expf(v - mx);
    float sm = e;
#pragma unroll
    for (int off = 32; off; off >>= 1) sm += __shfl_xor(sm, off);
    s[(size_t)gw * QL + lane] = e / sm;
    if (lane == 0) smax[gw] = mx;
}

// ---------------------------------------------------------------------------
__global__ __launch_bounds__(512)
void bw_k(const float* __restrict__ smax, float* __restrict__ bw)
{
    int b = blockIdx.x, c = threadIdx.x;
    int lane = c & 63, wid = c >> 6;
    __shared__ float red[8];
    float v = smax[b * CL + c];
    float mx = v;
#pragma unroll
    for (int off = 32; off; off >>= 1) mx = fmaxf(mx, __shfl_xor(mx, off));
    if (lane == 0) red[wid] = mx;
    __syncthreads();
    float bm = red[0];
#pragma unroll
    for (int w = 1; w < 8; ++w) bm = fmaxf(bm, red[w]);
    float e = expf(v - bm);
    float sm = e;
#pragma unroll
    for (int off = 32; off; off >>= 1) sm += __shfl_xor(sm, off);
    __syncthreads();
    if (lane == 0) red[wid] = sm;
    __syncthreads();
    float ts = 0.f;
#pragma unroll
    for (int w = 0; w < 8; ++w) ts += red[w];
    bw[b * CL + c] = e / ts;
}

// ---------------------------------------------------------------------------
__global__ __launch_bounds__(256)
void q2c_k(const float* __restrict__ bw, const float* __restrict__ co,
           float* __restrict__ q2c)
{
    int b = blockIdx.x, d = threadIdx.x;
    float acc = 0.f;
    for (int c = 0; c < CL; ++c)
        acc += bw[b * CL + c] * co[((size_t)b * CL + c) * 256 + d];
    q2c[b * 256 + d] = acc;
}

// ---------------------------------------------------------------------------
__global__ __launch_bounds__(256)
void c2q_g(const float* __restrict__ a, const float* __restrict__ qo,
           const float* __restrict__ co, const float* __restrict__ q2c,
           float* __restrict__ g)
{
    int b  = blockIdx.x;
    int c  = blockIdx.y * 64 + (threadIdx.x >> 2);
    int gq = threadIdx.x & 3;

    float4 acc[16];
#pragma unroll
    for (int jj = 0; jj < 16; ++jj) acc[jj] = make_float4(0.f, 0.f, 0.f, 0.f);

    const float* ar = a + ((size_t)b * CL + c) * QL;
    for (int q = 0; q < QL; ++q) {
        float av = ar[q];
        const float* qr = qo + ((size_t)b * QL + q) * 256;
#pragma unroll
        for (int jj = 0; jj < 16; ++jj) {
            float4 qv = *(const float4*)&qr[4 * gq + 16 * jj];
            acc[jj].x += av * qv.x; acc[jj].y += av * qv.y;
            acc[jj].z += av * qv.z; acc[jj].w += av * qv.w;
        }
    }
    size_t gbase = ((size_t)b * CL + c) * 1024;
    const float* corow = co + ((size_t)b * CL + c) * 256;
    const float* q2cr  = q2c + b * 256;
#pragma unroll
    for (int jj = 0; jj < 16; ++jj) {
        int d = 4 * gq + 16 * jj;
        float4 cv = *(const float4*)&corow[d];
        float4 qc = *(const float4*)&q2cr[d];
        float4 cq = acc[jj];
        *(float4*)&g[gbase + d] = cv;
        *(float4*)&g[gbase + 256 + d] = cq;
        float4 t;
        t.x = cv.x * cq.x; t.y = cv.y * cq.y; t.z = cv.z * cq.z; t.w = cv.w * cq.w;
        *(float4*)&g[gbase + 512 + d] = t;
        t.x = cv.x * qc.x; t.y = cv.y * qc.y; t.z = cv.z * qc.z; t.w = cv.w * qc.w;
        *(float4*)&g[gbase + 768 + d] = t;
    }
}

// ---------------------------------------------------------------------------
__global__ void logits_k(const float* __restrict__ g, const float* __restrict__ m,
                         const float* __restrict__ m2o,
                         const float* __restrict__ p1wg, const float* __restrict__ p1wm,
                         const float* __restrict__ p1b,
                         const float* __restrict__ p2wg, const float* __restrict__ p2wm,
                         const float* __restrict__ p2b,
                         float* __restrict__ lp1, float* __restrict__ lp2)
{
    int row  = (int)((blockIdx.x * blockDim.x + threadIdx.x) >> 6);
    int lane = threadIdx.x & 63;
    const float* gr = g + (size_t)row * 1024;
    float s1 = 0.f, s2 = 0.f;
    for (int d = lane; d < 1024; d += 64) {
        float gv = gr[d];
        s1 += gv * p1wg[d];
        s2 += gv * p2wg[d];
    }
    const float* mr  = m   + (size_t)row * 256;
    const float* m2r = m2o + (size_t)row * 256;
    for (int d = lane; d < 256; d += 64) {
        s1 += mr[d] * p1wm[d];
        s2 += m2r[d] * p2wm[d];
    }
#pragma unroll
    for (int off = 32; off; off >>= 1) {
        s1 += __shfl_down(s1, off);
        s2 += __shfl_down(s2, off);
    }
    if (lane == 0) {
        lp1[row] = s1 + p1b[0];
        lp2[row] = s2 + p2b[0];
    }
}

// ---------------------------------------------------------------------------
__global__ __launch_bounds__(512)
void masked_softmax(const float* __restrict__ lp1, const float* __restrict__ lp2,
                    const int* __restrict__ p, float* __restrict__ out)
{
    int b = blockIdx.x, c = threadIdx.x;
    int lane = c & 63, wid = c >> 6;
    const float* lp = blockIdx.y ? lp2 : lp1;
    float* o = out + (size_t)blockIdx.y * BB * CL;

    __shared__ float red[8];
    float v = (p[b * CL + c] != 0) ? lp[b * CL + c] : -INFINITY;
    float mx = v;
#pragma unroll
    for (int off = 32; off; off >>= 1) mx = fmaxf(mx, __shfl_xor(mx, off));
    if (lane == 0) red[wid] = mx;
    __syncthreads();
    float bm = red[0];
#pragma unroll
    for (int w = 1; w < 8; ++w) bm = fmaxf(bm, red[w]);
    float e = expf(v - bm);
    float sm = e;
#pragma unroll
    for (int off = 32; off; off >>= 1) sm += __shfl_xor(sm, off);
    __syncthreads();
    if (lane == 0) red[wid] = sm;
    __syncthreads();
    float ts = 0.f;
#pragma unroll
    for (int w = 0; w < 8; ++w) ts += red[w];
    o[b * CL + c] = e / ts;
}

// ---------------------------------------------------------------------------
extern "C" void kernel_launch(void* const* d_in, const int* in_sizes, int n_in,
                              void* d_out, int out_size, void* d_ws, size_t ws_size,
                              hipStream_t stream)
{
    const int*   p        = (const int*)d_in[0];
    const int*   q        = (const int*)d_in[1];
    const float* emb      = (const float*)d_in[2];
    const float* qenc_Wih = (const float*)d_in[3];
    const float* qenc_Whh = (const float*)d_in[4];
    const float* qenc_b   = (const float*)d_in[5];
    const float* penc_Wih = (const float*)d_in[6];
    const float* penc_Whh = (const float*)d_in[7];
    const float* penc_b   = (const float*)d_in[8];
    const float* m1_Wih   = (const float*)d_in[9];
    const float* m1_Whh   = (const float*)d_in[10];
    const float* m1_b     = (const float*)d_in[11];
    const float* m2_Wih   = (const float*)d_in[12];
    const float* m2_Whh   = (const float*)d_in[13];
    const float* m2_b     = (const float*)d_in[14];
    const float* out_Wih  = (const float*)d_in[15];
    const float* out_Whh  = (const float*)d_in[16];
    const float* out_b    = (const float*)d_in[17];
    const float* att_wc   = (const float*)d_in[18];
    const float* att_wq   = (const float*)d_in[19];
    const float* att_wcq  = (const float*)d_in[20];
    const float* att_b    = (const float*)d_in[21];
    const float* p1_wg    = (const float*)d_in[22];
    const float* p1_wm    = (const float*)d_in[23];
    const float* p1_b     = (const float*)d_in[24];
    const float* p2_wg    = (const float*)d_in[25];
    const float* p2_wm    = (const float*)d_in[26];
    const float* p2_b     = (const float*)d_in[27];

    float* ws = (float*)d_ws;
    size_t off = 0;
    auto alloc = [&](size_t n) { float* r = ws + off; off += n; return r; };
    auto allocU = [&](size_t nsh) { ushort* r = (ushort*)(ws + off); off += (nsh + 1) / 2; return r; };

    const size_t NC = (size_t)BB * CL;     // 32768
    const size_t NQ = (size_t)BB * QL;     // 4096

    float* xgA  = alloc(2 * NC * GATES);   // gate preacts, reused per layer
    float* gbuf = alloc(NC * 1024);        // g  (xgQ aliases its head: dead before g written)
    float* xgQ  = gbuf;
    float* co   = alloc(NC * 256);
    float* qo   = alloc(NQ * 256);
    float* sbuf = alloc(NC * QL);          // s, then a (in place)
    float* cw   = alloc(NC);
    float* qw   = alloc(NQ);
    float* smax = alloc(NC);
    float* bw   = alloc(NC);
    float* q2c  = alloc((size_t)BB * 256);
    float* mmid = alloc(NC * 256);
    float* mbuf = alloc(NC * 256);
    float* m2o  = alloc(NC * 256);
    float* lp1  = alloc(NC);
    float* lp2  = alloc(NC);
    // bf16 weight planes: [3][1024][Ksp]
    ushort* WqP  = allocU((size_t)3 * 1024 * 320);
    ushort* WpP  = allocU((size_t)3 * 1024 * 320);
    ushort* Wm1P = allocU((size_t)3 * 1024 * 1024);
    ushort* Wm2P = allocU((size_t)3 * 1024 * 256);
    ushort* WoP  = allocU((size_t)3 * 1024 * 256);
    (void)ws_size; (void)in_sizes; (void)n_in; (void)out_size;

    // ---- weight splits ----
    splitW_k<<<dim3(1024 * 80 / 256), 256, 0, stream>>>(qenc_Wih, WqP, 300, 320);
    splitW_k<<<dim3(1024 * 80 / 256), 256, 0, stream>>>(penc_Wih, WpP, 300, 320);
    splitW_k<<<dim3(1024 * 256 / 256), 256, 0, stream>>>(m1_Wih, Wm1P, 1024, 1024);
    splitW_k<<<dim3(1024 * 64 / 256), 256, 0, stream>>>(m2_Wih, Wm2P, 256, 256);
    splitW_k<<<dim3(1024 * 64 / 256), 256, 0, stream>>>(out_Wih, WoP, 256, 256);

    // ---- encoders (P and Q scans in one launch via z) ----
    gemm_bf16x3<<<dim3((int)(NQ / TM), 4, 2), 256, 0, stream>>>(emb, q, WqP, qenc_b, xgQ, (int)NQ, 300, 320);
    gemm_bf16x3<<<dim3((int)(NC / TM), 4, 2), 256, 0, stream>>>(emb, p, WpP, penc_b, xgA, (int)NC, 300, 320);
    lstm_scan5<<<dim3(BB, 2, 2), 256, 0, stream>>>(xgA, penc_Whh, co, CL,
                                                   xgQ, qenc_Whh, qo, QL);

    // ---- attention ----
    rowdot<<<dim3((int)(NC * 64 / 256)), 256, 0, stream>>>(co, att_wc, cw, (int)NC, 256);
    rowdot<<<dim3((int)(NQ * 64 / 256)), 256, 0, stream>>>(qo, att_wq, qw, (int)NQ, 256);
    att_s<<<dim3(BB, CL / 64), 256, 0, stream>>>(co, qo, cw, qw, att_wcq, att_b, sbuf);
    softmax_q<<<dim3((int)(NC * 64 / 256)), 256, 0, stream>>>(sbuf, smax);
    bw_k<<<dim3(BB), 512, 0, stream>>>(smax, bw);
    q2c_k<<<dim3(BB), 256, 0, stream>>>(bw, co, q2c);
    c2q_g<<<dim3(BB, CL / 64), 256, 0, stream>>>(sbuf, qo, co, q2c, gbuf);

    // ---- modeling layers ----
    gemm_bf16x3<<<dim3((int)(NC / TM), 4, 2), 256, 0, stream>>>(gbuf, nullptr, Wm1P, m1_b, xgA, (int)NC, 1024, 1024);
    lstm_scan5<<<dim3(BB, 2, 1), 256, 0, stream>>>(xgA, m1_Whh, mmid, CL,
                                                   xgA, m1_Whh, mmid, CL);
    gemm_bf16x3<<<dim3((int)(NC / TM), 4, 2), 256, 0, stream>>>(mmid, nullptr, Wm2P, m2_b, xgA, (int)NC, 256, 256);
    lstm_scan5<<<dim3(BB, 2, 1), 256, 0, stream>>>(xgA, m2_Whh, mbuf, CL,
                                                   xgA, m2_Whh, mbuf, CL);
    gemm_bf16x3<<<dim3((int)(NC / TM), 4, 2), 256, 0, stream>>>(mbuf, nullptr, WoP, out_b, xgA, (int)NC, 256, 256);
    lstm_scan5<<<dim3(BB, 2, 1), 256, 0, stream>>>(xgA, out_Whh, m2o, CL,
                                                   xgA, out_Whh, m2o, CL);

    // ---- output ----
    logits_k<<<dim3((int)(NC * 64 / 256)), 256, 0, stream>>>(gbuf, mbuf, m2o,
        p1_wg, p1_wm, p1_b, p2_wg, p2_wm, p2_b, lp1, lp2);
    masked_softmax<<<dim3(BB, 2), 512, 0, stream>>>(lp1, lp2, p, (float*)d_out);
}

// Round 7
// 3688.110 us; speedup vs baseline: 1.3601x; 1.3472x over previous
//
#include <hip/hip_runtime.h>
#include <math.h>
#include <stdint.h>

#define HD    128      // hidden
#define GATES 512      // 4H
#define BB    64       // batch
#define CL    512      // context len
#define QL    64       // query len

#define TM 128
#define TN 128
#define TK 32

typedef __attribute__((ext_vector_type(8))) short short8_t;
typedef __attribute__((ext_vector_type(4))) short short4_t;
typedef __attribute__((ext_vector_type(4))) float f32x4;

__device__ __forceinline__ float fast_sigmoid(float x) {
    float e = __builtin_amdgcn_exp2f(-1.44269504f * x);
    return __builtin_amdgcn_rcpf(1.f + e);
}
__device__ __forceinline__ float fast_tanh(float x) {
    float e = __builtin_amdgcn_exp2f(2.88539008f * x);
    float r = __builtin_amdgcn_rcpf(e + 1.f);
    return 1.f - 2.f * r;
}

// ---------------------------------------------------------------------------
// Split W (rows=1024, K) fp32 into 3 bf16 planes, each (1024, Ksp), padded.
// ---------------------------------------------------------------------------
__global__ __launch_bounds__(256)
void splitW_k(const float* __restrict__ W, ushort* __restrict__ P, int K, int Ksp)
{
    int idx = blockIdx.x * 256 + threadIdx.x;
    int per_row = Ksp >> 2;
    int total = 1024 * per_row;
    if (idx >= total) return;
    int row = idx / per_row;
    int c4  = (idx - row * per_row) * 4;

    short4_t o1, o2, o3;
#pragma unroll
    for (int e = 0; e < 4; ++e) {
        int k = c4 + e;
        float x = (k < K) ? W[(size_t)row * K + k] : 0.f;
        uint32_t u1 = __float_as_uint(x) & 0xffff0000u;
        float r1 = x - __uint_as_float(u1);
        uint32_t u2 = __float_as_uint(r1) & 0xffff0000u;
        float r2 = r1 - __uint_as_float(u2);
        uint32_t u3 = __float_as_uint(r2) & 0xffff0000u;
        o1[e] = (short)(u1 >> 16);
        o2[e] = (short)(u2 >> 16);
        o3[e] = (short)(u3 >> 16);
    }
    size_t base = (size_t)row * Ksp + c4;
    size_t ps = (size_t)1024 * Ksp;
    *reinterpret_cast<short4_t*>(&P[base]) = o1;
    *reinterpret_cast<short4_t*>(&P[ps + base]) = o2;
    *reinterpret_cast<short4_t*>(&P[2 * ps + base]) = o3;
}

// ---------------------------------------------------------------------------
// MFMA GEMM, bf16x3 split (6 cross-term MFMAs per k-tile).
// ---------------------------------------------------------------------------
__global__ __launch_bounds__(256)
void gemm_bf16x3(const float* __restrict__ A, const int* __restrict__ gidx,
                 const ushort* __restrict__ Wpl, const float* __restrict__ bias,
                 float* __restrict__ C, int M, int K, int Ksp)
{
    const int dir  = blockIdx.z;
    const int m0   = blockIdx.x * TM;
    const int n0   = blockIdx.y * TN;
    const int tid  = threadIdx.x;
    const int lane = tid & 63;
    const int wid  = tid >> 6;
    const int wm   = (wid >> 1) * 64;
    const int wn   = (wid & 1) * 64;

    __shared__ __align__(16) ushort As[3][TM * TK];
    __shared__ __align__(16) ushort Bs[3][TN * TK];

    const int ar = tid >> 3;
    const int ac = (tid & 7) * 4;

    size_t arow[4];
#pragma unroll
    for (int r = 0; r < 4; ++r) {
        int m = m0 + ar + r * 32;
        arow[r] = gidx ? (size_t)gidx[m] : (size_t)m;
    }

    f32x4 acc[4][4];
#pragma unroll
    for (int i = 0; i < 4; ++i)
#pragma unroll
        for (int j = 0; j < 4; ++j) acc[i][j] = (f32x4)0.f;

    const size_t wps    = (size_t)1024 * Ksp;
    const size_t wdbase = (size_t)dir * 512 * Ksp;

    for (int k0 = 0; k0 < Ksp; k0 += TK) {
#pragma unroll
        for (int r = 0; r < 4; ++r) {
            float4 v = make_float4(0.f, 0.f, 0.f, 0.f);
            if (k0 + ac < K) v = *(const float4*)(A + arow[r] * K + k0 + ac);
            float xs[4] = {v.x, v.y, v.z, v.w};
            short4_t o1, o2, o3;
#pragma unroll
            for (int e = 0; e < 4; ++e) {
                uint32_t u1 = __float_as_uint(xs[e]) & 0xffff0000u;
                float r1 = xs[e] - __uint_as_float(u1);
                uint32_t u2 = __float_as_uint(r1) & 0xffff0000u;
                float r2 = r1 - __uint_as_float(u2);
                uint32_t u3 = __float_as_uint(r2) & 0xffff0000u;
                o1[e] = (short)(u1 >> 16);
                o2[e] = (short)(u2 >> 16);
                o3[e] = (short)(u3 >> 16);
            }
            int wb = (ar + r * 32) * TK + ac;
            *reinterpret_cast<short4_t*>(&As[0][wb]) = o1;
            *reinterpret_cast<short4_t*>(&As[1][wb]) = o2;
            *reinterpret_cast<short4_t*>(&As[2][wb]) = o3;
        }
#pragma unroll
        for (int t = 0; t < 6; ++t) {
            int chunk = wid * 6 + t;
            int pl = chunk >> 3;
            int ch = chunk & 7;
            int rrow = ch * 16 + (lane >> 2);
            const ushort* src = Wpl + (size_t)pl * wps + wdbase +
                                (size_t)(n0 + rrow) * Ksp + k0 + (lane & 3) * 8;
            ushort* dst = &Bs[pl][ch * 512];
            __builtin_amdgcn_global_load_lds(
                reinterpret_cast<const __attribute__((address_space(1))) void*>(
                    reinterpret_cast<uintptr_t>(src)),
                reinterpret_cast<__attribute__((address_space(3))) void*>(
                    reinterpret_cast<uintptr_t>(dst)),
                16, 0, 0);
        }
        __syncthreads();

        const int koff = (lane >> 4) * 8;
        short8_t bf0[4], bf1[4], bf2[4];
#pragma unroll
        for (int j = 0; j < 4; ++j) {
            int nrow = wn + j * 16 + (lane & 15);
            bf0[j] = *reinterpret_cast<const short8_t*>(&Bs[0][nrow * TK + koff]);
            bf1[j] = *reinterpret_cast<const short8_t*>(&Bs[1][nrow * TK + koff]);
            bf2[j] = *reinterpret_cast<const short8_t*>(&Bs[2][nrow * TK + koff]);
        }
#pragma unroll
        for (int i = 0; i < 4; ++i) {
            int mrow = wm + i * 16 + (lane & 15);
            short8_t a1 = *reinterpret_cast<const short8_t*>(&As[0][mrow * TK + koff]);
            short8_t a2 = *reinterpret_cast<const short8_t*>(&As[1][mrow * TK + koff]);
            short8_t a3 = *reinterpret_cast<const short8_t*>(&As[2][mrow * TK + koff]);
#pragma unroll
            for (int j = 0; j < 4; ++j) {
                f32x4 c = acc[i][j];
                c = __builtin_amdgcn_mfma_f32_16x16x32_bf16(a1, bf0[j], c, 0, 0, 0);
                c = __builtin_amdgcn_mfma_f32_16x16x32_bf16(a1, bf1[j], c, 0, 0, 0);
                c = __builtin_amdgcn_mfma_f32_16x16x32_bf16(a2, bf0[j], c, 0, 0, 0);
                c = __builtin_amdgcn_mfma_f32_16x16x32_bf16(a2, bf1[j], c, 0, 0, 0);
                c = __builtin_amdgcn_mfma_f32_16x16x32_bf16(a1, bf2[j], c, 0, 0, 0);
                c = __builtin_amdgcn_mfma_f32_16x16x32_bf16(a3, bf0[j], c, 0, 0, 0);
                acc[i][j] = c;
            }
        }
        __syncthreads();
    }

    float* Cd = C + (size_t)dir * M * 512;
#pragma unroll
    for (int j = 0; j < 4; ++j) {
        int col = n0 + wn + j * 16 + (lane & 15);
        float bv = bias[dir * 512 + col];
#pragma unroll
        for (int i = 0; i < 4; ++i) {
            int rbase = m0 + wm + i * 16 + ((lane >> 4) << 2);
#pragma unroll
            for (int r = 0; r < 4; ++r)
                Cd[(size_t)(rbase + r) * 512 + col] = acc[i][j][r] + bv;
        }
    }
}

// ---------------------------------------------------------------------------
// LSTM scan v6 = v2 structure + weights PINNED in VGPRs.
// Block per (batch, dir[, layer via z]); 512 threads; thread j owns gate row
// j with Whh[j][0..127] held in 128 VGPRs (asm-pinned so the compiler cannot
// rematerialize the loads -> no 256KB/step L2 weight re-read).
// __launch_bounds__(512,2): 2 waves/SIMD -> 256-VGPR budget, 1 block/CU.
// ---------------------------------------------------------------------------
__global__ __launch_bounds__(512, 2)
void lstm_scan6(const float* __restrict__ xgP, const float* __restrict__ WhhP,
                float* __restrict__ hoP, int TP,
                const float* __restrict__ xgQ, const float* __restrict__ WhhQ,
                float* __restrict__ hoQ, int TQ)
{
    const int b   = blockIdx.x;
    const int dir = blockIdx.y;
    const int j   = threadIdx.x;

    const float* xg; const float* Whh; float* ho; int T;
    if (blockIdx.z == 0) { xg = xgP; Whh = WhhP; ho = hoP; T = TP; }
    else                 { xg = xgQ; Whh = WhhQ; ho = hoQ; T = TQ; }

    const float* xgd = xg + (size_t)dir * BB * T * GATES;
    const float* wr  = Whh + ((size_t)dir * GATES + j) * HD;

    float4 w[32];
#pragma unroll
    for (int kk = 0; kk < 32; ++kk) w[kk] = *(const float4*)(wr + kk * 4);
    // Pin: make the loaded values opaque so they stay resident in VGPRs.
#pragma unroll
    for (int kk = 0; kk < 32; ++kk)
        asm volatile("" : "+v"(w[kk].x), "+v"(w[kk].y), "+v"(w[kk].z), "+v"(w[kk].w));

    __shared__ __align__(16) float hs[HD];
    __shared__ float gs[GATES];

    if (j < HD) hs[j] = 0.f;
    float c = 0.f;
    __syncthreads();

    int t = dir ? (T - 1) : 0;
    const int dt = dir ? -1 : 1;
    const int gtype = j >> 7;            // 0:i 1:f 2:g 3:o (wave-uniform)

    float xcur = xgd[((size_t)b * T + t) * GATES + j];

    for (int step = 0; step < T; ++step) {
        int tn = t + dt;
        float xnext = (step + 1 < T) ? xgd[((size_t)b * T + tn) * GATES + j] : 0.f;

        float av[8];
        av[0] = xcur;
#pragma unroll
        for (int u = 1; u < 8; ++u) av[u] = 0.f;
#pragma unroll
        for (int kk = 0; kk < 32; ++kk) {
            float4 h4 = *(const float4*)&hs[kk * 4];
            float a = av[kk & 7];
            a += w[kk].x * h4.x;
            a += w[kk].y * h4.y;
            a += w[kk].z * h4.z;
            a += w[kk].w * h4.w;
            av[kk & 7] = a;
        }
        float pre = ((av[0] + av[4]) + (av[1] + av[5])) +
                    ((av[2] + av[6]) + (av[3] + av[7]));
        float act = (gtype == 2) ? fast_tanh(pre) : fast_sigmoid(pre);
        gs[j] = act;
        __syncthreads();
        if (j < HD) {
            float ig = gs[j], fg = gs[HD + j], gg = gs[2 * HD + j], og = gs[3 * HD + j];
            c = fg * c + ig * gg;
            float h = og * fast_tanh(c);
            hs[j] = h;
            ho[((size_t)b * T + t) * 256 + dir * HD + j] = h;
        }
        __syncthreads();
        xcur = xnext;
        t = tn;
    }
}

// ---------------------------------------------------------------------------
__global__ void rowdot(const float* __restrict__ X, const float* __restrict__ w,
                       float* __restrict__ out, int N, int D)
{
    int gw   = (int)((blockIdx.x * blockDim.x + threadIdx.x) >> 6);
    int lane = threadIdx.x & 63;
    if (gw >= N) return;
    const float* xp = X + (size_t)gw * D;
    float s = 0.f;
    for (int d = lane; d < D; d += 64) s += xp[d] * w[d];
#pragma unroll
    for (int off = 32; off; off >>= 1) s += __shfl_down(s, off);
    if (lane == 0) out[gw] = s;
}

// ---------------------------------------------------------------------------
__global__ __launch_bounds__(256)
void att_s(const float* __restrict__ co, const float* __restrict__ qo,
           const float* __restrict__ cw, const float* __restrict__ qw,
           const float* __restrict__ wcq, const float* __restrict__ attb,
           float* __restrict__ s)
{
    int b  = blockIdx.x;
    int c0 = blockIdx.y * 64;
    int tid = threadIdx.x;
    int tq = tid & 15, trc = tid >> 4;
    int cbase = c0 + trc * 4, qbase = tq * 4;

    float acc[4][4];
#pragma unroll
    for (int i = 0; i < 4; ++i)
#pragma unroll
        for (int j = 0; j < 4; ++j) acc[i][j] = 0.f;

    for (int d = 0; d < 256; d += 4) {
        float4 wv = *(const float4*)&wcq[d];
        float4 cv[4], qv[4];
#pragma unroll
        for (int i = 0; i < 4; ++i) {
            float4 v = *(const float4*)&co[((size_t)b * CL + cbase + i) * 256 + d];
            cv[i].x = v.x * wv.x; cv[i].y = v.y * wv.y;
            cv[i].z = v.z * wv.z; cv[i].w = v.w * wv.w;
        }
#pragma unroll
        for (int j = 0; j < 4; ++j)
            qv[j] = *(const float4*)&qo[((size_t)b * QL + qbase + j) * 256 + d];
#pragma unroll
        for (int i = 0; i < 4; ++i)
#pragma unroll
            for (int j = 0; j < 4; ++j)
                acc[i][j] += cv[i].x * qv[j].x + cv[i].y * qv[j].y +
                             cv[i].z * qv[j].z + cv[i].w * qv[j].w;
    }
    float ab = attb[0];
#pragma unroll
    for (int i = 0; i < 4; ++i) {
        float cwv = cw[b * CL + cbase + i];
#pragma unroll
        for (int j = 0; j < 4; ++j) {
            s[((size_t)b * CL + cbase + i) * QL + qbase + j] =
                acc[i][j] + cwv + qw[b * QL + qbase + j] + ab;
        }
    }
}

// ---------------------------------------------------------------------------
__global__ void softmax_q(float* __restrict__ s, float* __restrict__ smax)
{
    int gw   = (int)((blockIdx.x * blockDim.x + threadIdx.x) >> 6);
    int lane = threadIdx.x & 63;
    float v = s[(size_t)gw * QL + lane];
    float mx = v;
#pragma unroll
    for (int off = 32; off; off >>= 1) mx = fmaxf(mx, __shfl_xor(mx, off));
    float e = expf(v - mx);
    float sm = e;
#pragma unroll
    for (int off = 32; off; off >>= 1) sm += __shfl_xor(sm, off);
    s[(size_t)gw * QL + lane] = e / sm;
    if (lane == 0) smax[gw] = mx;
}

// ---------------------------------------------------------------------------
__global__ __launch_bounds__(512)
void bw_k(const float* __restrict__ smax, float* __restrict__ bw)
{
    int b = blockIdx.x, c = threadIdx.x;
    int lane = c & 63, wid = c >> 6;
    __shared__ float red[8];
    float v = smax[b * CL + c];
    float mx = v;
#pragma unroll
    for (int off = 32; off; off >>= 1) mx = fmaxf(mx, __shfl_xor(mx, off));
    if (lane == 0) red[wid] = mx;
    __syncthreads();
    float bm = red[0];
#pragma unroll
    for (int w = 1; w < 8; ++w) bm = fmaxf(bm, red[w]);
    float e = expf(v - bm);
    float sm = e;
#pragma unroll
    for (int off = 32; off; off >>= 1) sm += __shfl_xor(sm, off);
    __syncthreads();
    if (lane == 0) red[wid] = sm;
    __syncthreads();
    float ts = 0.f;
#pragma unroll
    for (int w = 0; w < 8; ++w) ts += red[w];
    bw[b * CL + c] = e / ts;
}

// ---------------------------------------------------------------------------
__global__ __launch_bounds__(256)
void q2c_k(const float* __restrict__ bw, const float* __restrict__ co,
           float* __restrict__ q2c)
{
    int b = blockIdx.x, d = threadIdx.x;
    float acc = 0.f;
    for (int c = 0; c < CL; ++c)
        acc += bw[b * CL + c] * co[((size_t)b * CL + c) * 256 + d];
    q2c[b * 256 + d] = acc;
}

// ---------------------------------------------------------------------------
__global__ __launch_bounds__(256)
void c2q_g(const float* __restrict__ a, const float* __restrict__ qo,
           const float* __restrict__ co, const float* __restrict__ q2c,
           float* __restrict__ g)
{
    int b  = blockIdx.x;
    int c  = blockIdx.y * 64 + (threadIdx.x >> 2);
    int gq = threadIdx.x & 3;

    float4 acc[16];
#pragma unroll
    for (int jj = 0; jj < 16; ++jj) acc[jj] = make_float4(0.f, 0.f, 0.f, 0.f);

    const float* ar = a + ((size_t)b * CL + c) * QL;
    for (int q = 0; q < QL; ++q) {
        float av = ar[q];
        const float* qr = qo + ((size_t)b * QL + q) * 256;
#pragma unroll
        for (int jj = 0; jj < 16; ++jj) {
            float4 qv = *(const float4*)&qr[4 * gq + 16 * jj];
            acc[jj].x += av * qv.x; acc[jj].y += av * qv.y;
            acc[jj].z += av * qv.z; acc[jj].w += av * qv.w;
        }
    }
    size_t gbase = ((size_t)b * CL + c) * 1024;
    const float* corow = co + ((size_t)b * CL + c) * 256;
    const float* q2cr  = q2c + b * 256;
#pragma unroll
    for (int jj = 0; jj < 16; ++jj) {
        int d = 4 * gq + 16 * jj;
        float4 cv = *(const float4*)&corow[d];
        float4 qc = *(const float4*)&q2cr[d];
        float4 cq = acc[jj];
        *(float4*)&g[gbase + d] = cv;
        *(float4*)&g[gbase + 256 + d] = cq;
        float4 t;
        t.x = cv.x * cq.x; t.y = cv.y * cq.y; t.z = cv.z * cq.z; t.w = cv.w * cq.w;
        *(float4*)&g[gbase + 512 + d] = t;
        t.x = cv.x * qc.x; t.y = cv.y * qc.y; t.z = cv.z * qc.z; t.w = cv.w * qc.w;
        *(float4*)&g[gbase + 768 + d] = t;
    }
}

// ---------------------------------------------------------------------------
__global__ void logits_k(const float* __restrict__ g, const float* __restrict__ m,
                         const float* __restrict__ m2o,
                         const float* __restrict__ p1wg, const float* __restrict__ p1wm,
                         const float* __restrict__ p1b,
                         const float* __restrict__ p2wg, const float* __restrict__ p2wm,
                         const float* __restrict__ p2b,
                         float* __restrict__ lp1, float* __restrict__ lp2)
{
    int row  = (int)((blockIdx.x * blockDim.x + threadIdx.x) >> 6);
    int lane = threadIdx.x & 63;
    const float* gr = g + (size_t)row * 1024;
    float s1 = 0.f, s2 = 0.f;
    for (int d = lane; d < 1024; d += 64) {
        float gv = gr[d];
        s1 += gv * p1wg[d];
        s2 += gv * p2wg[d];
    }
    const float* mr  = m   + (size_t)row * 256;
    const float* m2r = m2o + (size_t)row * 256;
    for (int d = lane; d < 256; d += 64) {
        s1 += mr[d] * p1wm[d];
        s2 += m2r[d] * p2wm[d];
    }
#pragma unroll
    for (int off = 32; off; off >>= 1) {
        s1 += __shfl_down(s1, off);
        s2 += __shfl_down(s2, off);
    }
    if (lane == 0) {
        lp1[row] = s1 + p1b[0];
        lp2[row] = s2 + p2b[0];
    }
}

// ---------------------------------------------------------------------------
__global__ __launch_bounds__(512)
void masked_softmax(const float* __restrict__ lp1, const float* __restrict__ lp2,
                    const int* __restrict__ p, float* __restrict__ out)
{
    int b = blockIdx.x, c = threadIdx.x;
    int lane = c & 63, wid = c >> 6;
    const float* lp = blockIdx.y ? lp2 : lp1;
    float* o = out + (size_t)blockIdx.y * BB * CL;

    __shared__ float red[8];
    float v = (p[b * CL + c] != 0) ? lp[b * CL + c] : -INFINITY;
    float mx = v;
#pragma unroll
    for (int off = 32; off; off >>= 1) mx = fmaxf(mx, __shfl_xor(mx, off));
    if (lane == 0) red[wid] = mx;
    __syncthreads();
    float bm = red[0];
#pragma unroll
    for (int w = 1; w < 8; ++w) bm = fmaxf(bm, red[w]);
    float e = expf(v - bm);
    float sm = e;
#pragma unroll
    for (int off = 32; off; off >>= 1) sm += __shfl_xor(sm, off);
    __syncthreads();
    if (lane == 0) red[wid] = sm;
    __syncthreads();
    float ts = 0.f;
#pragma unroll
    for (int w = 0; w < 8; ++w) ts += red[w];
    o[b * CL + c] = e / ts;
}

// ---------------------------------------------------------------------------
extern "C" void kernel_launch(void* const* d_in, const int* in_sizes, int n_in,
                              void* d_out, int out_size, void* d_ws, size_t ws_size,
                              hipStream_t stream)
{
    const int*   p        = (const int*)d_in[0];
    const int*   q        = (const int*)d_in[1];
    const float* emb      = (const float*)d_in[2];
    const float* qenc_Wih = (const float*)d_in[3];
    const float* qenc_Whh = (const float*)d_in[4];
    const float* qenc_b   = (const float*)d_in[5];
    const float* penc_Wih = (const float*)d_in[6];
    const float* penc_Whh = (const float*)d_in[7];
    const float* penc_b   = (const float*)d_in[8];
    const float* m1_Wih   = (const float*)d_in[9];
    const float* m1_Whh   = (const float*)d_in[10];
    const float* m1_b     = (const float*)d_in[11];
    const float* m2_Wih   = (const float*)d_in[12];
    const float* m2_Whh   = (const float*)d_in[13];
    const float* m2_b     = (const float*)d_in[14];
    const float* out_Wih  = (const float*)d_in[15];
    const float* out_Whh  = (const float*)d_in[16];
    const float* out_b    = (const float*)d_in[17];
    const float* att_wc   = (const float*)d_in[18];
    const float* att_wq   = (const float*)d_in[19];
    const float* att_wcq  = (const float*)d_in[20];
    const float* att_b    = (const float*)d_in[21];
    const float* p1_wg    = (const float*)d_in[22];
    const float* p1_wm    = (const float*)d_in[23];
    const float* p1_b     = (const float*)d_in[24];
    const float* p2_wg    = (const float*)d_in[25];
    const float* p2_wm    = (const float*)d_in[26];
    const float* p2_b     = (const float*)d_in[27];

    float* ws = (float*)d_ws;
    size_t off = 0;
    auto alloc = [&](size_t n) { float* r = ws + off; off += n; return r; };
    auto allocU = [&](size_t nsh) { ushort* r = (ushort*)(ws + off); off += (nsh + 1) / 2; return r; };

    const size_t NC = (size_t)BB * CL;     // 32768
    const size_t NQ = (size_t)BB * QL;     // 4096

    float* xgA  = alloc(2 * NC * GATES);   // gate preacts, reused per layer
    float* gbuf = alloc(NC * 1024);        // g  (xgQ aliases its head: dead before g written)
    float* xgQ  = gbuf;
    float* co   = alloc(NC * 256);
    float* qo   = alloc(NQ * 256);
    float* sbuf = alloc(NC * QL);          // s, then a (in place)
    float* cw   = alloc(NC);
    float* qw   = alloc(NQ);
    float* smax = alloc(NC);
    float* bw   = alloc(NC);
    float* q2c  = alloc((size_t)BB * 256);
    float* mmid = alloc(NC * 256);
    float* mbuf = alloc(NC * 256);
    float* m2o  = alloc(NC * 256);
    float* lp1  = alloc(NC);
    float* lp2  = alloc(NC);
    // bf16 weight planes: [3][1024][Ksp]
    ushort* WqP  = allocU((size_t)3 * 1024 * 320);
    ushort* WpP  = allocU((size_t)3 * 1024 * 320);
    ushort* Wm1P = allocU((size_t)3 * 1024 * 1024);
    ushort* Wm2P = allocU((size_t)3 * 1024 * 256);
    ushort* WoP  = allocU((size_t)3 * 1024 * 256);
    (void)ws_size; (void)in_sizes; (void)n_in; (void)out_size;

    // ---- weight splits ----
    splitW_k<<<dim3(1024 * 80 / 256), 256, 0, stream>>>(qenc_Wih, WqP, 300, 320);
    splitW_k<<<dim3(1024 * 80 / 256), 256, 0, stream>>>(penc_Wih, WpP, 300, 320);
    splitW_k<<<dim3(1024 * 256 / 256), 256, 0, stream>>>(m1_Wih, Wm1P, 1024, 1024);
    splitW_k<<<dim3(1024 * 64 / 256), 256, 0, stream>>>(m2_Wih, Wm2P, 256, 256);
    splitW_k<<<dim3(1024 * 64 / 256), 256, 0, stream>>>(out_Wih, WoP, 256, 256);

    // ---- encoders (P and Q scans in one launch via z) ----
    gemm_bf16x3<<<dim3((int)(NQ / TM), 4, 2), 256, 0, stream>>>(emb, q, WqP, qenc_b, xgQ, (int)NQ, 300, 320);
    gemm_bf16x3<<<dim3((int)(NC / TM), 4, 2), 256, 0, stream>>>(emb, p, WpP, penc_b, xgA, (int)NC, 300, 320);
    lstm_scan6<<<dim3(BB, 2, 2), 512, 0, stream>>>(xgA, penc_Whh, co, CL,
                                                   xgQ, qenc_Whh, qo, QL);

    // ---- attention ----
    rowdot<<<dim3((int)(NC * 64 / 256)), 256, 0, stream>>>(co, att_wc, cw, (int)NC, 256);
    rowdot<<<dim3((int)(NQ * 64 / 256)), 256, 0, stream>>>(qo, att_wq, qw, (int)NQ, 256);
    att_s<<<dim3(BB, CL / 64), 256, 0, stream>>>(co, qo, cw, qw, att_wcq, att_b, sbuf);
    softmax_q<<<dim3((int)(NC * 64 / 256)), 256, 0, stream>>>(sbuf, smax);
    bw_k<<<dim3(BB), 512, 0, stream>>>(smax, bw);
    q2c_k<<<dim3(BB), 256, 0, stream>>>(bw, co, q2c);
    c2q_g<<<dim3(BB, CL / 64), 256, 0, stream>>>(sbuf, qo, co, q2c, gbuf);

    // ---- modeling layers ----
    gemm_bf16x3<<<dim3((int)(NC / TM), 4, 2), 256, 0, stream>>>(gbuf, nullptr, Wm1P, m1_b, xgA, (int)NC, 1024, 1024);
    lstm_scan6<<<dim3(BB, 2, 1), 512, 0, stream>>>(xgA, m1_Whh, mmid, CL,
                                                   xgA, m1_Whh, mmid, CL);
    gemm_bf16x3<<<dim3((int)(NC / TM), 4, 2), 256, 0, stream>>>(mmid, nullptr, Wm2P, m2_b, xgA, (int)NC, 256, 256);
    lstm_scan6<<<dim3(BB, 2, 1), 512, 0, stream>>>(xgA, m2_Whh, mbuf, CL,
                                                   xgA, m2_Whh, mbuf, CL);
    gemm_bf16x3<<<dim3((int)(NC / TM), 4, 2), 256, 0, stream>>>(mbuf, nullptr, WoP, out_b, xgA, (int)NC, 256, 256);
    lstm_scan6<<<dim3(BB, 2, 1), 512, 0, stream>>>(xgA, out_Whh, m2o, CL,
                                                   xgA, out_Whh, m2o, CL);

    // ---- output ----
    logits_k<<<dim3((int)(NC * 64 / 256)), 256, 0, stream>>>(gbuf, mbuf, m2o,
        p1_wg, p1_wm, p1_b, p2_wg, p2_wm, p2_b, lp1, lp2);
    masked_softmax<<<dim3(BB, 2), 512, 0, stream>>>(lp1, lp2, p, (float*)d_out);
}

// Round 8
// 2836.552 us; speedup vs baseline: 1.7684x; 1.3002x over previous
//
#include <hip/hip_runtime.h>
#include <math.h>
#include <stdint.h>

#define HD    128      // hidden
#define GATES 512      // 4H
#define BB    64       // batch
#define CL    512      // context len
#define QL    64       // query len

#define TM 128
#define TN 128
#define TK 32

typedef __attribute__((ext_vector_type(8))) short short8_t;
typedef __attribute__((ext_vector_type(4))) short short4_t;
typedef __attribute__((ext_vector_type(4))) float f32x4;

__device__ __forceinline__ float fast_sigmoid(float x) {
    float e = __builtin_amdgcn_exp2f(-1.44269504f * x);
    return __builtin_amdgcn_rcpf(1.f + e);
}
__device__ __forceinline__ float fast_tanh(float x) {
    float e = __builtin_amdgcn_exp2f(2.88539008f * x);
    float r = __builtin_amdgcn_rcpf(e + 1.f);
    return 1.f - 2.f * r;
}
// sum across the 4 lanes of a quad (s = lane&3) via DPP quad_perm; all lanes
// end with the full sum. Pure VALU - no DS pipe.
__device__ __forceinline__ float quad_sum(float v) {
    int y = __builtin_amdgcn_mov_dpp(__float_as_int(v), 0xB1, 0xF, 0xF, 0); // l^1
    float s = v + __int_as_float(y);
    int z = __builtin_amdgcn_mov_dpp(__float_as_int(s), 0x4E, 0xF, 0xF, 0); // l^2
    return s + __int_as_float(z);
}
// h LDS layout: pos(e) = e + (e>>5)*4  (slice-offset so the 4 concurrent
// slice reads hit distinct banks). Size 140 floats.
#define HPOS(e) ((e) + (((e) >> 5) << 2))

// ---------------------------------------------------------------------------
// Split W (rows=1024, K) fp32 into 3 bf16 planes, each (1024, Ksp), padded.
// ---------------------------------------------------------------------------
__global__ __launch_bounds__(256)
void splitW_k(const float* __restrict__ W, ushort* __restrict__ P, int K, int Ksp)
{
    int idx = blockIdx.x * 256 + threadIdx.x;
    int per_row = Ksp >> 2;
    int total = 1024 * per_row;
    if (idx >= total) return;
    int row = idx / per_row;
    int c4  = (idx - row * per_row) * 4;

    short4_t o1, o2, o3;
#pragma unroll
    for (int e = 0; e < 4; ++e) {
        int k = c4 + e;
        float x = (k < K) ? W[(size_t)row * K + k] : 0.f;
        uint32_t u1 = __float_as_uint(x) & 0xffff0000u;
        float r1 = x - __uint_as_float(u1);
        uint32_t u2 = __float_as_uint(r1) & 0xffff0000u;
        float r2 = r1 - __uint_as_float(u2);
        uint32_t u3 = __float_as_uint(r2) & 0xffff0000u;
        o1[e] = (short)(u1 >> 16);
        o2[e] = (short)(u2 >> 16);
        o3[e] = (short)(u3 >> 16);
    }
    size_t base = (size_t)row * Ksp + c4;
    size_t ps = (size_t)1024 * Ksp;
    *reinterpret_cast<short4_t*>(&P[base]) = o1;
    *reinterpret_cast<short4_t*>(&P[ps + base]) = o2;
    *reinterpret_cast<short4_t*>(&P[2 * ps + base]) = o3;
}

// ---------------------------------------------------------------------------
// MFMA GEMM, bf16x3 split (6 cross-term MFMAs per k-tile).
// ---------------------------------------------------------------------------
__global__ __launch_bounds__(256)
void gemm_bf16x3(const float* __restrict__ A, const int* __restrict__ gidx,
                 const ushort* __restrict__ Wpl, const float* __restrict__ bias,
                 float* __restrict__ C, int M, int K, int Ksp)
{
    const int dir  = blockIdx.z;
    const int m0   = blockIdx.x * TM;
    const int n0   = blockIdx.y * TN;
    const int tid  = threadIdx.x;
    const int lane = tid & 63;
    const int wid  = tid >> 6;
    const int wm   = (wid >> 1) * 64;
    const int wn   = (wid & 1) * 64;

    __shared__ __align__(16) ushort As[3][TM * TK];
    __shared__ __align__(16) ushort Bs[3][TN * TK];

    const int ar = tid >> 3;
    const int ac = (tid & 7) * 4;

    size_t arow[4];
#pragma unroll
    for (int r = 0; r < 4; ++r) {
        int m = m0 + ar + r * 32;
        arow[r] = gidx ? (size_t)gidx[m] : (size_t)m;
    }

    f32x4 acc[4][4];
#pragma unroll
    for (int i = 0; i < 4; ++i)
#pragma unroll
        for (int j = 0; j < 4; ++j) acc[i][j] = (f32x4)0.f;

    const size_t wps    = (size_t)1024 * Ksp;
    const size_t wdbase = (size_t)dir * 512 * Ksp;

    for (int k0 = 0; k0 < Ksp; k0 += TK) {
#pragma unroll
        for (int r = 0; r < 4; ++r) {
            float4 v = make_float4(0.f, 0.f, 0.f, 0.f);
            if (k0 + ac < K) v = *(const float4*)(A + arow[r] * K + k0 + ac);
            float xs[4] = {v.x, v.y, v.z, v.w};
            short4_t o1, o2, o3;
#pragma unroll
            for (int e = 0; e < 4; ++e) {
                uint32_t u1 = __float_as_uint(xs[e]) & 0xffff0000u;
                float r1 = xs[e] - __uint_as_float(u1);
                uint32_t u2 = __float_as_uint(r1) & 0xffff0000u;
                float r2 = r1 - __uint_as_float(u2);
                uint32_t u3 = __float_as_uint(r2) & 0xffff0000u;
                o1[e] = (short)(u1 >> 16);
                o2[e] = (short)(u2 >> 16);
                o3[e] = (short)(u3 >> 16);
            }
            int wb = (ar + r * 32) * TK + ac;
            *reinterpret_cast<short4_t*>(&As[0][wb]) = o1;
            *reinterpret_cast<short4_t*>(&As[1][wb]) = o2;
            *reinterpret_cast<short4_t*>(&As[2][wb]) = o3;
        }
#pragma unroll
        for (int t = 0; t < 6; ++t) {
            int chunk = wid * 6 + t;
            int pl = chunk >> 3;
            int ch = chunk & 7;
            int rrow = ch * 16 + (lane >> 2);
            const ushort* src = Wpl + (size_t)pl * wps + wdbase +
                                (size_t)(n0 + rrow) * Ksp + k0 + (lane & 3) * 8;
            ushort* dst = &Bs[pl][ch * 512];
            __builtin_amdgcn_global_load_lds(
                reinterpret_cast<const __attribute__((address_space(1))) void*>(
                    reinterpret_cast<uintptr_t>(src)),
                reinterpret_cast<__attribute__((address_space(3))) void*>(
                    reinterpret_cast<uintptr_t>(dst)),
                16, 0, 0);
        }
        __syncthreads();

        const int koff = (lane >> 4) * 8;
        short8_t bf0[4], bf1[4], bf2[4];
#pragma unroll
        for (int j = 0; j < 4; ++j) {
            int nrow = wn + j * 16 + (lane & 15);
            bf0[j] = *reinterpret_cast<const short8_t*>(&Bs[0][nrow * TK + koff]);
            bf1[j] = *reinterpret_cast<const short8_t*>(&Bs[1][nrow * TK + koff]);
            bf2[j] = *reinterpret_cast<const short8_t*>(&Bs[2][nrow * TK + koff]);
        }
#pragma unroll
        for (int i = 0; i < 4; ++i) {
            int mrow = wm + i * 16 + (lane & 15);
            short8_t a1 = *reinterpret_cast<const short8_t*>(&As[0][mrow * TK + koff]);
            short8_t a2 = *reinterpret_cast<const short8_t*>(&As[1][mrow * TK + koff]);
            short8_t a3 = *reinterpret_cast<const short8_t*>(&As[2][mrow * TK + koff]);
#pragma unroll
            for (int j = 0; j < 4; ++j) {
                f32x4 c = acc[i][j];
                c = __builtin_amdgcn_mfma_f32_16x16x32_bf16(a1, bf0[j], c, 0, 0, 0);
                c = __builtin_amdgcn_mfma_f32_16x16x32_bf16(a1, bf1[j], c, 0, 0, 0);
                c = __builtin_amdgcn_mfma_f32_16x16x32_bf16(a2, bf0[j], c, 0, 0, 0);
                c = __builtin_amdgcn_mfma_f32_16x16x32_bf16(a2, bf1[j], c, 0, 0, 0);
                c = __builtin_amdgcn_mfma_f32_16x16x32_bf16(a1, bf2[j], c, 0, 0, 0);
                c = __builtin_amdgcn_mfma_f32_16x16x32_bf16(a3, bf0[j], c, 0, 0, 0);
                acc[i][j] = c;
            }
        }
        __syncthreads();
    }

    float* Cd = C + (size_t)dir * M * 512;
#pragma unroll
    for (int j = 0; j < 4; ++j) {
        int col = n0 + wn + j * 16 + (lane & 15);
        float bv = bias[dir * 512 + col];
#pragma unroll
        for (int i = 0; i < 4; ++i) {
            int rbase = m0 + wm + i * 16 + ((lane >> 4) << 2);
#pragma unroll
            for (int r = 0; r < 4; ++r)
                Cd[(size_t)(rbase + r) * 512 + col] = acc[i][j][r] + bv;
        }
    }
}

// ---------------------------------------------------------------------------
// LSTM scan v7 (DPP): block per (batch, dir[, layer via z]); 512 threads.
// Thread (u = w*16 + (lane>>2), s = lane&3) computes partials for ALL 4 gates
// of hidden unit u over k-slice [32s, 32s+32): weights 4x8 float4 = 128 VGPRs
// (amdgpu_waves_per_eu(2,2): grid gives 1 block/CU = 2 waves/SIMD regardless,
// so the allocator may use the full 256-VGPR budget - no remat/spill).
// Per step: 8 ds_read_b128 (bank-swizzled h) + 128 FMA + quad_perm DPP
// reduce (no DS) + redundant in-quad cell update + 1 masked h write into a
// double-buffered hs + ONE barrier.
// ---------------------------------------------------------------------------
__global__ __launch_bounds__(512) __attribute__((amdgpu_waves_per_eu(2, 2)))
void lstm_dpp(const float* __restrict__ xgP, const float* __restrict__ WhhP,
              float* __restrict__ hoP, int TP,
              const float* __restrict__ xgQ, const float* __restrict__ WhhQ,
              float* __restrict__ hoQ, int TQ)
{
    const int b    = blockIdx.x;
    const int dir  = blockIdx.y;
    const int tid  = threadIdx.x;
    const int l    = tid & 63;
    const int w    = tid >> 6;
    const int u    = w * 16 + (l >> 2);   // hidden unit 0..127
    const int s    = l & 3;               // k-slice 0..3

    const float* xg; const float* Whh; float* ho; int T;
    if (blockIdx.z == 0) { xg = xgP; Whh = WhhP; ho = hoP; T = TP; }
    else                 { xg = xgQ; Whh = WhhQ; ho = hoQ; T = TQ; }

    const float* xgd = xg + (size_t)dir * BB * T * GATES;

    // weights: wv[g][j] = Whh[(dir*512 + g*128 + u)*128 + s*32 + j*4 ..+3]
    float4 wv[4][8];
#pragma unroll
    for (int g = 0; g < 4; ++g) {
        const float* wr = Whh + ((size_t)dir * GATES + g * 128 + u) * HD + s * 32;
#pragma unroll
        for (int j = 0; j < 8; ++j) wv[g][j] = *(const float4*)(wr + j * 4);
    }

    __shared__ __align__(16) float hs[2][140];

    if (tid < 140) { hs[0][tid] = 0.f; }
    float c = 0.f;

    int t = dir ? (T - 1) : 0;
    const int dt = dir ? -1 : 1;

    float xc[4], xn[4];
#pragma unroll
    for (int g = 0; g < 4; ++g)
        xc[g] = xgd[((size_t)b * T + t) * GATES + g * 128 + u];

    const int rdbase = HPOS(s * 32);      // = s*36, 16B-aligned
    __syncthreads();

    for (int step = 0; step < T; ++step) {
        const int tn = t + dt;
        const int rbuf = step & 1, wbuf = rbuf ^ 1;

        // prefetch next step's xg under this step's compute
        if (step + 1 < T) {
#pragma unroll
            for (int g = 0; g < 4; ++g)
                xn[g] = xgd[((size_t)b * T + tn) * GATES + g * 128 + u];
        }

        float ps0 = 0.f, ps1 = 0.f, ps2 = 0.f, ps3 = 0.f;
#pragma unroll
        for (int j = 0; j < 8; ++j) {
            float4 h4 = *(const float4*)&hs[rbuf][rdbase + j * 4];
            ps0 += wv[0][j].x * h4.x + wv[0][j].y * h4.y + wv[0][j].z * h4.z + wv[0][j].w * h4.w;
            ps1 += wv[1][j].x * h4.x + wv[1][j].y * h4.y + wv[1][j].z * h4.z + wv[1][j].w * h4.w;
            ps2 += wv[2][j].x * h4.x + wv[2][j].y * h4.y + wv[2][j].z * h4.z + wv[2][j].w * h4.w;
            ps3 += wv[3][j].x * h4.x + wv[3][j].y * h4.y + wv[3][j].z * h4.z + wv[3][j].w * h4.w;
        }
        // reduce across the 4 slices (quad lanes) - pure VALU
        float pre0 = quad_sum(ps0) + xc[0];
        float pre1 = quad_sum(ps1) + xc[1];
        float pre2 = quad_sum(ps2) + xc[2];
        float pre3 = quad_sum(ps3) + xc[3];

        // redundant (consistent) cell update in all 4 lanes of the quad
        float ig = fast_sigmoid(pre0);
        float fg = fast_sigmoid(pre1);
        float gg = fast_tanh(pre2);
        float og = fast_sigmoid(pre3);
        c = fg * c + ig * gg;
        float h = og * fast_tanh(c);

        if (s == 0) {
            hs[wbuf][HPOS(u)] = h;
            ho[((size_t)b * T + t) * 256 + dir * HD + u] = h;
        }
        __syncthreads();

#pragma unroll
        for (int g = 0; g < 4; ++g) xc[g] = xn[g];
        t = tn;
    }
}

// ---------------------------------------------------------------------------
__global__ void rowdot(const float* __restrict__ X, const float* __restrict__ w,
                       float* __restrict__ out, int N, int D)
{
    int gw   = (int)((blockIdx.x * blockDim.x + threadIdx.x) >> 6);
    int lane = threadIdx.x & 63;
    if (gw >= N) return;
    const float* xp = X + (size_t)gw * D;
    float s = 0.f;
    for (int d = lane; d < D; d += 64) s += xp[d] * w[d];
#pragma unroll
    for (int off = 32; off; off >>= 1) s += __shfl_down(s, off);
    if (lane == 0) out[gw] = s;
}

// ---------------------------------------------------------------------------
__global__ __launch_bounds__(256)
void att_s(const float* __restrict__ co, const float* __restrict__ qo,
           const float* __restrict__ cw, const float* __restrict__ qw,
           const float* __restrict__ wcq, const float* __restrict__ attb,
           float* __restrict__ s)
{
    int b  = blockIdx.x;
    int c0 = blockIdx.y * 64;
    int tid = threadIdx.x;
    int tq = tid & 15, trc = tid >> 4;
    int cbase = c0 + trc * 4, qbase = tq * 4;

    float acc[4][4];
#pragma unroll
    for (int i = 0; i < 4; ++i)
#pragma unroll
        for (int j = 0; j < 4; ++j) acc[i][j] = 0.f;

    for (int d = 0; d < 256; d += 4) {
        float4 wv = *(const float4*)&wcq[d];
        float4 cv[4], qv[4];
#pragma unroll
        for (int i = 0; i < 4; ++i) {
            float4 v = *(const float4*)&co[((size_t)b * CL + cbase + i) * 256 + d];
            cv[i].x = v.x * wv.x; cv[i].y = v.y * wv.y;
            cv[i].z = v.z * wv.z; cv[i].w = v.w * wv.w;
        }
#pragma unroll
        for (int j = 0; j < 4; ++j)
            qv[j] = *(const float4*)&qo[((size_t)b * QL + qbase + j) * 256 + d];
#pragma unroll
        for (int i = 0; i < 4; ++i)
#pragma unroll
            for (int j = 0; j < 4; ++j)
                acc[i][j] += cv[i].x * qv[j].x + cv[i].y * qv[j].y +
                             cv[i].z * qv[j].z + cv[i].w * qv[j].w;
    }
    float ab = attb[0];
#pragma unroll
    for (int i = 0; i < 4; ++i) {
        float cwv = cw[b * CL + cbase + i];
#pragma unroll
        for (int j = 0; j < 4; ++j) {
            s[((size_t)b * CL + cbase + i) * QL + qbase + j] =
                acc[i][j] + cwv + qw[b * QL + qbase + j] + ab;
        }
    }
}

// ---------------------------------------------------------------------------
__global__ void softmax_q(float* __restrict__ s, float* __restrict__ smax)
{
    int gw   = (int)((blockIdx.x * blockDim.x + threadIdx.x) >> 6);
    int lane = threadIdx.x & 63;
    float v = s[(size_t)gw * QL + lane];
    float mx = v;
#pragma unroll
    for (int off = 32; off; off >>= 1) mx = fmaxf(mx, __shfl_xor(mx, off));
    float e = expf(v - mx);
    float sm = e;
#pragma unroll
    for (int off = 32; off; off >>= 1) sm += __shfl_xor(sm, off);
    s[(size_t)gw * QL + lane] = e / sm;
    if (lane == 0) smax[gw] = mx;
}

// ---------------------------------------------------------------------------
__global__ __launch_bounds__(512)
void bw_k(const float* __restrict__ smax, float* __restrict__ bw)
{
    int b = blockIdx.x, c = threadIdx.x;
    int lane = c & 63, wid = c >> 6;
    __shared__ float red[8];
    float v = smax[b * CL + c];
    float mx = v;
#pragma unroll
    for (int off = 32; off; off >>= 1) mx = fmaxf(mx, __shfl_xor(mx, off));
    if (lane == 0) red[wid] = mx;
    __syncthreads();
    float bm = red[0];
#pragma unroll
    for (int w = 1; w < 8; ++w) bm = fmaxf(bm, red[w]);
    float e = expf(v - bm);
    float sm = e;
#pragma unroll
    for (int off = 32; off; off >>= 1) sm += __shfl_xor(sm, off);
    __syncthreads();
    if (lane == 0) red[wid] = sm;
    __syncthreads();
    float ts = 0.f;
#pragma unroll
    for (int w = 0; w < 8; ++w) ts += red[w];
    bw[b * CL + c] = e / ts;
}

// ---------------------------------------------------------------------------
__global__ __launch_bounds__(256)
void q2c_k(const float* __restrict__ bw, const float* __restrict__ co,
           float* __restrict__ q2c)
{
    int b = blockIdx.x, d = threadIdx.x;
    float acc = 0.f;
    for (int c = 0; c < CL; ++c)
        acc += bw[b * CL + c] * co[((size_t)b * CL + c) * 256 + d];
    q2c[b * 256 + d] = acc;
}

// ---------------------------------------------------------------------------
__global__ __launch_bounds__(256)
void c2q_g(const float* __restrict__ a, const float* __restrict__ qo,
           const float* __restrict__ co, const float* __restrict__ q2c,
           float* __restrict__ g)
{
    int b  = blockIdx.x;
    int c  = blockIdx.y * 64 + (threadIdx.x >> 2);
    int gq = threadIdx.x & 3;

    float4 acc[16];
#pragma unroll
    for (int jj = 0; jj < 16; ++jj) acc[jj] = make_float4(0.f, 0.f, 0.f, 0.f);

    const float* ar = a + ((size_t)b * CL + c) * QL;
    for (int q = 0; q < QL; ++q) {
        float av = ar[q];
        const float* qr = qo + ((size_t)b * QL + q) * 256;
#pragma unroll
        for (int jj = 0; jj < 16; ++jj) {
            float4 qv = *(const float4*)&qr[4 * gq + 16 * jj];
            acc[jj].x += av * qv.x; acc[jj].y += av * qv.y;
            acc[jj].z += av * qv.z; acc[jj].w += av * qv.w;
        }
    }
    size_t gbase = ((size_t)b * CL + c) * 1024;
    const float* corow = co + ((size_t)b * CL + c) * 256;
    const float* q2cr  = q2c + b * 256;
#pragma unroll
    for (int jj = 0; jj < 16; ++jj) {
        int d = 4 * gq + 16 * jj;
        float4 cv = *(const float4*)&corow[d];
        float4 qc = *(const float4*)&q2cr[d];
        float4 cq = acc[jj];
        *(float4*)&g[gbase + d] = cv;
        *(float4*)&g[gbase + 256 + d] = cq;
        float4 t;
        t.x = cv.x * cq.x; t.y = cv.y * cq.y; t.z = cv.z * cq.z; t.w = cv.w * cq.w;
        *(float4*)&g[gbase + 512 + d] = t;
        t.x = cv.x * qc.x; t.y = cv.y * qc.y; t.z = cv.z * qc.z; t.w = cv.w * qc.w;
        *(float4*)&g[gbase + 768 + d] = t;
    }
}

// ---------------------------------------------------------------------------
__global__ void logits_k(const float* __restrict__ g, const float* __restrict__ m,
                         const float* __restrict__ m2o,
                         const float* __restrict__ p1wg, const float* __restrict__ p1wm,
                         const float* __restrict__ p1b,
                         const float* __restrict__ p2wg, const float* __restrict__ p2wm,
                         const float* __restrict__ p2b,
                         float* __restrict__ lp1, float* __restrict__ lp2)
{
    int row  = (int)((blockIdx.x * blockDim.x + threadIdx.x) >> 6);
    int lane = threadIdx.x & 63;
    const float* gr = g + (size_t)row * 1024;
    float s1 = 0.f, s2 = 0.f;
    for (int d = lane; d < 1024; d += 64) {
        float gv = gr[d];
        s1 += gv * p1wg[d];
        s2 += gv * p2wg[d];
    }
    const float* mr  = m   + (size_t)row * 256;
    const float* m2r = m2o + (size_t)row * 256;
    for (int d = lane; d < 256; d += 64) {
        s1 += mr[d] * p1wm[d];
        s2 += m2r[d] * p2wm[d];
    }
#pragma unroll
    for (int off = 32; off; off >>= 1) {
        s1 += __shfl_down(s1, off);
        s2 += __shfl_down(s2, off);
    }
    if (lane == 0) {
        lp1[row] = s1 + p1b[0];
        lp2[row] = s2 + p2b[0];
    }
}

// ---------------------------------------------------------------------------
__global__ __launch_bounds__(512)
void masked_softmax(const float* __restrict__ lp1, const float* __restrict__ lp2,
                    const int* __restrict__ p, float* __restrict__ out)
{
    int b = blockIdx.x, c = threadIdx.x;
    int lane = c & 63, wid = c >> 6;
    const float* lp = blockIdx.y ? lp2 : lp1;
    float* o = out + (size_t)blockIdx.y * BB * CL;

    __shared__ float red[8];
    float v = (p[b * CL + c] != 0) ? lp[b * CL + c] : -INFINITY;
    float mx = v;
#pragma unroll
    for (int off = 32; off; off >>= 1) mx = fmaxf(mx, __shfl_xor(mx, off));
    if (lane == 0) red[wid] = mx;
    __syncthreads();
    float bm = red[0];
#pragma unroll
    for (int w = 1; w < 8; ++w) bm = fmaxf(bm, red[w]);
    float e = expf(v - bm);
    float sm = e;
#pragma unroll
    for (int off = 32; off; off >>= 1) sm += __shfl_xor(sm, off);
    __syncthreads();
    if (lane == 0) red[wid] = sm;
    __syncthreads();
    float ts = 0.f;
#pragma unroll
    for (int w = 0; w < 8; ++w) ts += red[w];
    o[b * CL + c] = e / ts;
}

// ---------------------------------------------------------------------------
extern "C" void kernel_launch(void* const* d_in, const int* in_sizes, int n_in,
                              void* d_out, int out_size, void* d_ws, size_t ws_size,
                              hipStream_t stream)
{
    const int*   p        = (const int*)d_in[0];
    const int*   q        = (const int*)d_in[1];
    const float* emb      = (const float*)d_in[2];
    const float* qenc_Wih = (const float*)d_in[3];
    const float* qenc_Whh = (const float*)d_in[4];
    const float* qenc_b   = (const float*)d_in[5];
    const float* penc_Wih = (const float*)d_in[6];
    const float* penc_Whh = (const float*)d_in[7];
    const float* penc_b   = (const float*)d_in[8];
    const float* m1_Wih   = (const float*)d_in[9];
    const float* m1_Whh   = (const float*)d_in[10];
    const float* m1_b     = (const float*)d_in[11];
    const float* m2_Wih   = (const float*)d_in[12];
    const float* m2_Whh   = (const float*)d_in[13];
    const float* m2_b     = (const float*)d_in[14];
    const float* out_Wih  = (const float*)d_in[15];
    const float* out_Whh  = (const float*)d_in[16];
    const float* out_b    = (const float*)d_in[17];
    const float* att_wc   = (const float*)d_in[18];
    const float* att_wq   = (const float*)d_in[19];
    const float* att_wcq  = (const float*)d_in[20];
    const float* att_b    = (const float*)d_in[21];
    const float* p1_wg    = (const float*)d_in[22];
    const float* p1_wm    = (const float*)d_in[23];
    const float* p1_b     = (const float*)d_in[24];
    const float* p2_wg    = (const float*)d_in[25];
    const float* p2_wm    = (const float*)d_in[26];
    const float* p2_b     = (const float*)d_in[27];

    float* ws = (float*)d_ws;
    size_t off = 0;
    auto alloc = [&](size_t n) { float* r = ws + off; off += n; return r; };
    auto allocU = [&](size_t nsh) { ushort* r = (ushort*)(ws + off); off += (nsh + 1) / 2; return r; };

    const size_t NC = (size_t)BB * CL;     // 32768
    const size_t NQ = (size_t)BB * QL;     // 4096

    float* xgA  = alloc(2 * NC * GATES);   // gate preacts, reused per layer
    float* gbuf = alloc(NC * 1024);        // g  (xgQ aliases its head: dead before g written)
    float* xgQ  = gbuf;
    float* co   = alloc(NC * 256);
    float* qo   = alloc(NQ * 256);
    float* sbuf = alloc(NC * QL);          // s, then a (in place)
    float* cw   = alloc(NC);
    float* qw   = alloc(NQ);
    float* smax = alloc(NC);
    float* bw   = alloc(NC);
    float* q2c  = alloc((size_t)BB * 256);
    float* mmid = alloc(NC * 256);
    float* mbuf = alloc(NC * 256);
    float* m2o  = alloc(NC * 256);
    float* lp1  = alloc(NC);
    float* lp2  = alloc(NC);
    // bf16 weight planes: [3][1024][Ksp]
    ushort* WqP  = allocU((size_t)3 * 1024 * 320);
    ushort* WpP  = allocU((size_t)3 * 1024 * 320);
    ushort* Wm1P = allocU((size_t)3 * 1024 * 1024);
    ushort* Wm2P = allocU((size_t)3 * 1024 * 256);
    ushort* WoP  = allocU((size_t)3 * 1024 * 256);
    (void)ws_size; (void)in_sizes; (void)n_in; (void)out_size;

    // ---- weight splits ----
    splitW_k<<<dim3(1024 * 80 / 256), 256, 0, stream>>>(qenc_Wih, WqP, 300, 320);
    splitW_k<<<dim3(1024 * 80 / 256), 256, 0, stream>>>(penc_Wih, WpP, 300, 320);
    splitW_k<<<dim3(1024 * 256 / 256), 256, 0, stream>>>(m1_Wih, Wm1P, 1024, 1024);
    splitW_k<<<dim3(1024 * 64 / 256), 256, 0, stream>>>(m2_Wih, Wm2P, 256, 256);
    splitW_k<<<dim3(1024 * 64 / 256), 256, 0, stream>>>(out_Wih, WoP, 256, 256);

    // ---- encoders (P and Q scans in one launch via z) ----
    gemm_bf16x3<<<dim3((int)(NQ / TM), 4, 2), 256, 0, stream>>>(emb, q, WqP, qenc_b, xgQ, (int)NQ, 300, 320);
    gemm_bf16x3<<<dim3((int)(NC / TM), 4, 2), 256, 0, stream>>>(emb, p, WpP, penc_b, xgA, (int)NC, 300, 320);
    lstm_dpp<<<dim3(BB, 2, 2), 512, 0, stream>>>(xgA, penc_Whh, co, CL,
                                                 xgQ, qenc_Whh, qo, QL);

    // ---- attention ----
    rowdot<<<dim3((int)(NC * 64 / 256)), 256, 0, stream>>>(co, att_wc, cw, (int)NC, 256);
    rowdot<<<dim3((int)(NQ * 64 / 256)), 256, 0, stream>>>(qo, att_wq, qw, (int)NQ, 256);
    att_s<<<dim3(BB, CL / 64), 256, 0, stream>>>(co, qo, cw, qw, att_wcq, att_b, sbuf);
    softmax_q<<<dim3((int)(NC * 64 / 256)), 256, 0, stream>>>(sbuf, smax);
    bw_k<<<dim3(BB), 512, 0, stream>>>(smax, bw);
    q2c_k<<<dim3(BB), 256, 0, stream>>>(bw, co, q2c);
    c2q_g<<<dim3(BB, CL / 64), 256, 0, stream>>>(sbuf, qo, co, q2c, gbuf);

    // ---- modeling layers ----
    gemm_bf16x3<<<dim3((int)(NC / TM), 4, 2), 256, 0, stream>>>(gbuf, nullptr, Wm1P, m1_b, xgA, (int)NC, 1024, 1024);
    lstm_dpp<<<dim3(BB, 2, 1), 512, 0, stream>>>(xgA, m1_Whh, mmid, CL,
                                                 xgA, m1_Whh, mmid, CL);
    gemm_bf16x3<<<dim3((int)(NC / TM), 4, 2), 256, 0, stream>>>(mmid, nullptr, Wm2P, m2_b, xgA, (int)NC, 256, 256);
    lstm_dpp<<<dim3(BB, 2, 1), 512, 0, stream>>>(xgA, m2_Whh, mbuf, CL,
                                                 xgA, m2_Whh, mbuf, CL);
    gemm_bf16x3<<<dim3((int)(NC / TM), 4, 2), 256, 0, stream>>>(mbuf, nullptr, WoP, out_b, xgA, (int)NC, 256, 256);
    lstm_dpp<<<dim3(BB, 2, 1), 512, 0, stream>>>(xgA, out_Whh, m2o, CL,
                                                 xgA, out_Whh, m2o, CL);

    // ---- output ----
    logits_k<<<dim3((int)(NC * 64 / 256)), 256, 0, stream>>>(gbuf, mbuf, m2o,
        p1_wg, p1_wm, p1_b, p2_wg, p2_wm, p2_b, lp1, lp2);
    masked_softmax<<<dim3(BB, 2), 512, 0, stream>>>(lp1, lp2, p, (float*)d_out);
}

// Round 9
// 2770.557 us; speedup vs baseline: 1.8105x; 1.0238x over previous
//
#include <hip/hip_runtime.h>
#include <math.h>
#include <stdint.h>

#define HD    128      // hidden
#define GATES 512      // 4H
#define BB    64       // batch
#define CL    512      // context len
#define QL    64       // query len

#define TM 128
#define TN 128
#define TK 32
#define ASTR 40        // padded As row stride (ushorts): 80B, 16B-aligned, ~2-way banks

typedef __attribute__((ext_vector_type(8))) short short8_t;
typedef __attribute__((ext_vector_type(4))) short short4_t;
typedef __attribute__((ext_vector_type(4))) float f32x4;
typedef __attribute__((ext_vector_type(2))) float f32x2;

__device__ __forceinline__ float fast_sigmoid(float x) {
    float e = __builtin_amdgcn_exp2f(-1.44269504f * x);
    return __builtin_amdgcn_rcpf(1.f + e);
}
__device__ __forceinline__ float fast_tanh(float x) {
    float e = __builtin_amdgcn_exp2f(2.88539008f * x);
    float r = __builtin_amdgcn_rcpf(e + 1.f);
    return 1.f - 2.f * r;
}
// sum across the 4 lanes of a quad via DPP quad_perm; all lanes get the sum.
__device__ __forceinline__ float quad_sum(float v) {
    int y = __builtin_amdgcn_mov_dpp(__float_as_int(v), 0xB1, 0xF, 0xF, 0); // l^1
    float s = v + __int_as_float(y);
    int z = __builtin_amdgcn_mov_dpp(__float_as_int(s), 0x4E, 0xF, 0xF, 0); // l^2
    return s + __int_as_float(z);
}
#define HPOS(e) ((e) + (((e) >> 5) << 2))

// ---------------------------------------------------------------------------
// Split W (rows=1024, K) fp32 into 3 bf16 planes, each (1024, Ksp), padded.
// ---------------------------------------------------------------------------
__global__ __launch_bounds__(256)
void splitW_k(const float* __restrict__ W, ushort* __restrict__ P, int K, int Ksp)
{
    int idx = blockIdx.x * 256 + threadIdx.x;
    int per_row = Ksp >> 2;
    int total = 1024 * per_row;
    if (idx >= total) return;
    int row = idx / per_row;
    int c4  = (idx - row * per_row) * 4;

    short4_t o1, o2, o3;
#pragma unroll
    for (int e = 0; e < 4; ++e) {
        int k = c4 + e;
        float x = (k < K) ? W[(size_t)row * K + k] : 0.f;
        uint32_t u1 = __float_as_uint(x) & 0xffff0000u;
        float r1 = x - __uint_as_float(u1);
        uint32_t u2 = __float_as_uint(r1) & 0xffff0000u;
        float r2 = r1 - __uint_as_float(u2);
        uint32_t u3 = __float_as_uint(r2) & 0xffff0000u;
        o1[e] = (short)(u1 >> 16);
        o2[e] = (short)(u2 >> 16);
        o3[e] = (short)(u3 >> 16);
    }
    size_t base = (size_t)row * Ksp + c4;
    size_t ps = (size_t)1024 * Ksp;
    *reinterpret_cast<short4_t*>(&P[base]) = o1;
    *reinterpret_cast<short4_t*>(&P[ps + base]) = o2;
    *reinterpret_cast<short4_t*>(&P[2 * ps + base]) = o3;
}

// ---------------------------------------------------------------------------
// MFMA GEMM, bf16x3 split (6 cross-term MFMAs per k-tile).
// Grid: (8, M/128) - x = n0(0..3) + dir*4 fast-varying so the 8 blocks that
// read one A-tile are adjacent in dispatch order (A reuse in L2/L3).
// As rows padded to 40 ushorts; Bs XOR-16B swizzled (inverse swizzle applied
// to the per-lane GLOBAL source so global_load_lds dest stays linear).
// ---------------------------------------------------------------------------
__global__ __launch_bounds__(256)
void gemm_bf16x3(const float* __restrict__ A, const int* __restrict__ gidx,
                 const ushort* __restrict__ Wpl, const float* __restrict__ bias,
                 float* __restrict__ C, int M, int K, int Ksp)
{
    const int n0   = (blockIdx.x & 3) * TN / 1;      // n-tile within 512 gates
    const int dir  = blockIdx.x >> 2;
    const int m0   = blockIdx.y * TM;
    const int tid  = threadIdx.x;
    const int lane = tid & 63;
    const int wid  = tid >> 6;
    const int wm   = (wid >> 1) * 64;
    const int wn   = (wid & 1) * 64;

    __shared__ __align__(16) ushort As[3][TM * ASTR];
    __shared__ __align__(16) ushort Bs[3][TN * TK];

    const int ar = tid >> 3;
    const int ac = (tid & 7) * 4;

    size_t arow[4];
#pragma unroll
    for (int r = 0; r < 4; ++r) {
        int m = m0 + ar + r * 32;
        arow[r] = gidx ? (size_t)gidx[m] : (size_t)m;
    }

    f32x4 acc[4][4];
#pragma unroll
    for (int i = 0; i < 4; ++i)
#pragma unroll
        for (int j = 0; j < 4; ++j) acc[i][j] = (f32x4)0.f;

    const size_t wps    = (size_t)1024 * Ksp;
    const size_t wdbase = (size_t)dir * 512 * Ksp;

    for (int k0 = 0; k0 < Ksp; k0 += TK) {
        // ---- stage A: fp32 load, 3-way split, ds_write (padded rows) ----
#pragma unroll
        for (int r = 0; r < 4; ++r) {
            float4 v = make_float4(0.f, 0.f, 0.f, 0.f);
            if (k0 + ac < K) v = *(const float4*)(A + arow[r] * K + k0 + ac);
            float xs[4] = {v.x, v.y, v.z, v.w};
            short4_t o1, o2, o3;
#pragma unroll
            for (int e = 0; e < 4; ++e) {
                uint32_t u1 = __float_as_uint(xs[e]) & 0xffff0000u;
                float r1 = xs[e] - __uint_as_float(u1);
                uint32_t u2 = __float_as_uint(r1) & 0xffff0000u;
                float r2 = r1 - __uint_as_float(u2);
                uint32_t u3 = __float_as_uint(r2) & 0xffff0000u;
                o1[e] = (short)(u1 >> 16);
                o2[e] = (short)(u2 >> 16);
                o3[e] = (short)(u3 >> 16);
            }
            int wb = (ar + r * 32) * ASTR + ac;
            *reinterpret_cast<short4_t*>(&As[0][wb]) = o1;
            *reinterpret_cast<short4_t*>(&As[1][wb]) = o2;
            *reinterpret_cast<short4_t*>(&As[2][wb]) = o3;
        }
        // ---- stage B: global_load_lds, inverse-swizzled source ----
#pragma unroll
        for (int t = 0; t < 6; ++t) {
            int chunk = wid * 6 + t;
            int pl = chunk >> 3;
            int ch = chunk & 7;
            int rrow = ch * 16 + (lane >> 2);
            int ksw  = ((lane & 3) ^ ((rrow >> 1) & 3)) * 8;   // inverse swizzle
            const ushort* src = Wpl + (size_t)pl * wps + wdbase +
                                (size_t)(n0 + rrow) * Ksp + k0 + ksw;
            ushort* dst = &Bs[pl][ch * 512];
            __builtin_amdgcn_global_load_lds(
                reinterpret_cast<const __attribute__((address_space(1))) void*>(
                    reinterpret_cast<uintptr_t>(src)),
                reinterpret_cast<__attribute__((address_space(3))) void*>(
                    reinterpret_cast<uintptr_t>(dst)),
                16, 0, 0);
        }
        __syncthreads();

        const int koff = (lane >> 4) * 8;
        short8_t bf0[4], bf1[4], bf2[4];
#pragma unroll
        for (int j = 0; j < 4; ++j) {
            int nrow = wn + j * 16 + (lane & 15);
            int ks = (((lane >> 4) ^ ((nrow >> 1) & 3)) * 8);  // swizzled read
            bf0[j] = *reinterpret_cast<const short8_t*>(&Bs[0][nrow * TK + ks]);
            bf1[j] = *reinterpret_cast<const short8_t*>(&Bs[1][nrow * TK + ks]);
            bf2[j] = *reinterpret_cast<const short8_t*>(&Bs[2][nrow * TK + ks]);
        }
#pragma unroll
        for (int i = 0; i < 4; ++i) {
            int mrow = wm + i * 16 + (lane & 15);
            short8_t a1 = *reinterpret_cast<const short8_t*>(&As[0][mrow * ASTR + koff]);
            short8_t a2 = *reinterpret_cast<const short8_t*>(&As[1][mrow * ASTR + koff]);
            short8_t a3 = *reinterpret_cast<const short8_t*>(&As[2][mrow * ASTR + koff]);
#pragma unroll
            for (int j = 0; j < 4; ++j) {
                f32x4 c = acc[i][j];
                c = __builtin_amdgcn_mfma_f32_16x16x32_bf16(a1, bf0[j], c, 0, 0, 0);
                c = __builtin_amdgcn_mfma_f32_16x16x32_bf16(a1, bf1[j], c, 0, 0, 0);
                c = __builtin_amdgcn_mfma_f32_16x16x32_bf16(a2, bf0[j], c, 0, 0, 0);
                c = __builtin_amdgcn_mfma_f32_16x16x32_bf16(a2, bf1[j], c, 0, 0, 0);
                c = __builtin_amdgcn_mfma_f32_16x16x32_bf16(a1, bf2[j], c, 0, 0, 0);
                c = __builtin_amdgcn_mfma_f32_16x16x32_bf16(a3, bf0[j], c, 0, 0, 0);
                acc[i][j] = c;
            }
        }
        __syncthreads();
    }

    float* Cd = C + (size_t)dir * M * 512;
#pragma unroll
    for (int j = 0; j < 4; ++j) {
        int col = n0 + wn + j * 16 + (lane & 15);
        float bv = bias[dir * 512 + col];
#pragma unroll
        for (int i = 0; i < 4; ++i) {
            int rbase = m0 + wm + i * 16 + ((lane >> 4) << 2);
#pragma unroll
            for (int r = 0; r < 4; ++r)
                Cd[(size_t)(rbase + r) * 512 + col] = acc[i][j][r] + bv;
        }
    }
}

// ---------------------------------------------------------------------------
// LSTM scan v8 (DPP + packed fp32): block per (batch, dir[, layer via z]).
// Thread (u, s) computes 4-gate partials for unit u over k-slice [32s,32s+32)
// with weights in 128 VGPRs (f32x2 pairs -> v_pk_fma_f32, half the VALU
// instructions). quad_perm DPP reduce, redundant update, 1 barrier/step.
// ---------------------------------------------------------------------------
__global__ __launch_bounds__(512) __attribute__((amdgpu_waves_per_eu(2, 2)))
void lstm_dpp(const float* __restrict__ xgP, const float* __restrict__ WhhP,
              float* __restrict__ hoP, int TP,
              const float* __restrict__ xgQ, const float* __restrict__ WhhQ,
              float* __restrict__ hoQ, int TQ)
{
    const int b    = blockIdx.x;
    const int dir  = blockIdx.y;
    const int tid  = threadIdx.x;
    const int l    = tid & 63;
    const int w    = tid >> 6;
    const int u    = w * 16 + (l >> 2);   // hidden unit 0..127
    const int s    = l & 3;               // k-slice 0..3

    const float* xg; const float* Whh; float* ho; int T;
    if (blockIdx.z == 0) { xg = xgP; Whh = WhhP; ho = hoP; T = TP; }
    else                 { xg = xgQ; Whh = WhhQ; ho = hoQ; T = TQ; }

    const float* xgd = xg + (size_t)dir * BB * T * GATES;

    // weights as f32x2 pairs: wv2[g][j2] = Whh[(dir*512+g*128+u)*128 + s*32 + j2*2..+1]
    f32x2 wv2[4][16];
#pragma unroll
    for (int g = 0; g < 4; ++g) {
        const float* wr = Whh + ((size_t)dir * GATES + g * 128 + u) * HD + s * 32;
#pragma unroll
        for (int j = 0; j < 8; ++j) {
            float4 t4 = *(const float4*)(wr + j * 4);
            wv2[g][2 * j]     = f32x2{t4.x, t4.y};
            wv2[g][2 * j + 1] = f32x2{t4.z, t4.w};
        }
    }

    __shared__ __align__(16) float hs[2][140];

    if (tid < 140) { hs[0][tid] = 0.f; }
    float c = 0.f;

    int t = dir ? (T - 1) : 0;
    const int dt = dir ? -1 : 1;

    float xc[4], xn[4];
#pragma unroll
    for (int g = 0; g < 4; ++g)
        xc[g] = xgd[((size_t)b * T + t) * GATES + g * 128 + u];

    const int rdbase = HPOS(s * 32);
    __syncthreads();

    for (int step = 0; step < T; ++step) {
        const int tn = t + dt;
        const int rbuf = step & 1, wbuf = rbuf ^ 1;

        if (step + 1 < T) {
#pragma unroll
            for (int g = 0; g < 4; ++g)
                xn[g] = xgd[((size_t)b * T + tn) * GATES + g * 128 + u];
        }

        f32x2 p0 = {0.f, 0.f}, p1 = {0.f, 0.f}, p2 = {0.f, 0.f}, p3 = {0.f, 0.f};
#pragma unroll
        for (int j = 0; j < 8; ++j) {
            float4 h4 = *(const float4*)&hs[rbuf][rdbase + j * 4];
            f32x2 hl = {h4.x, h4.y}, hh = {h4.z, h4.w};
            p0 = __builtin_elementwise_fma(wv2[0][2 * j], hl, p0);
            p1 = __builtin_elementwise_fma(wv2[1][2 * j], hl, p1);
            p2 = __builtin_elementwise_fma(wv2[2][2 * j], hl, p2);
            p3 = __builtin_elementwise_fma(wv2[3][2 * j], hl, p3);
            p0 = __builtin_elementwise_fma(wv2[0][2 * j + 1], hh, p0);
            p1 = __builtin_elementwise_fma(wv2[1][2 * j + 1], hh, p1);
            p2 = __builtin_elementwise_fma(wv2[2][2 * j + 1], hh, p2);
            p3 = __builtin_elementwise_fma(wv2[3][2 * j + 1], hh, p3);
        }
        float pre0 = quad_sum(p0.x + p0.y) + xc[0];
        float pre1 = quad_sum(p1.x + p1.y) + xc[1];
        float pre2 = quad_sum(p2.x + p2.y) + xc[2];
        float pre3 = quad_sum(p3.x + p3.y) + xc[3];

        float ig = fast_sigmoid(pre0);
        float fg = fast_sigmoid(pre1);
        float gg = fast_tanh(pre2);
        float og = fast_sigmoid(pre3);
        c = fg * c + ig * gg;
        float h = og * fast_tanh(c);

        if (s == 0) {
            hs[wbuf][HPOS(u)] = h;
            ho[((size_t)b * T + t) * 256 + dir * HD + u] = h;
        }
        __syncthreads();

#pragma unroll
        for (int g = 0; g < 4; ++g) xc[g] = xn[g];
        t = tn;
    }
}

// ---------------------------------------------------------------------------
__global__ void rowdot(const float* __restrict__ X, const float* __restrict__ w,
                       float* __restrict__ out, int N, int D)
{
    int gw   = (int)((blockIdx.x * blockDim.x + threadIdx.x) >> 6);
    int lane = threadIdx.x & 63;
    if (gw >= N) return;
    const float* xp = X + (size_t)gw * D;
    float s = 0.f;
    for (int d = lane; d < D; d += 64) s += xp[d] * w[d];
#pragma unroll
    for (int off = 32; off; off >>= 1) s += __shfl_down(s, off);
    if (lane == 0) out[gw] = s;
}

// ---------------------------------------------------------------------------
__global__ __launch_bounds__(256)
void att_s(const float* __restrict__ co, const float* __restrict__ qo,
           const float* __restrict__ cw, const float* __restrict__ qw,
           const float* __restrict__ wcq, const float* __restrict__ attb,
           float* __restrict__ s)
{
    int b  = blockIdx.x;
    int c0 = blockIdx.y * 64;
    int tid = threadIdx.x;
    int tq = tid & 15, trc = tid >> 4;
    int cbase = c0 + trc * 4, qbase = tq * 4;

    float acc[4][4];
#pragma unroll
    for (int i = 0; i < 4; ++i)
#pragma unroll
        for (int j = 0; j < 4; ++j) acc[i][j] = 0.f;

    for (int d = 0; d < 256; d += 4) {
        float4 wv = *(const float4*)&wcq[d];
        float4 cv[4], qv[4];
#pragma unroll
        for (int i = 0; i < 4; ++i) {
            float4 v = *(const float4*)&co[((size_t)b * CL + cbase + i) * 256 + d];
            cv[i].x = v.x * wv.x; cv[i].y = v.y * wv.y;
            cv[i].z = v.z * wv.z; cv[i].w = v.w * wv.w;
        }
#pragma unroll
        for (int j = 0; j < 4; ++j)
            qv[j] = *(const float4*)&qo[((size_t)b * QL + qbase + j) * 256 + d];
#pragma unroll
        for (int i = 0; i < 4; ++i)
#pragma unroll
            for (int j = 0; j < 4; ++j)
                acc[i][j] += cv[i].x * qv[j].x + cv[i].y * qv[j].y +
                             cv[i].z * qv[j].z + cv[i].w * qv[j].w;
    }
    float ab = attb[0];
#pragma unroll
    for (int i = 0; i < 4; ++i) {
        float cwv = cw[b * CL + cbase + i];
#pragma unroll
        for (int j = 0; j < 4; ++j) {
            s[((size_t)b * CL + cbase + i) * QL + qbase + j] =
                acc[i][j] + cwv + qw[b * QL + qbase + j] + ab;
        }
    }
}

// ---------------------------------------------------------------------------
__global__ void softmax_q(float* __restrict__ s, float* __restrict__ smax)
{
    int gw   = (int)((blockIdx.x * blockDim.x + threadIdx.x) >> 6);
    int lane = threadIdx.x & 63;
    float v = s[(size_t)gw * QL + lane];
    float mx = v;
#pragma unroll
    for (int off = 32; off; off >>= 1) mx = fmaxf(mx, __shfl_xor(mx, off));
    float e = expf(v - mx);
    float sm = e;
#pragma unroll
    for (int off = 32; off; off >>= 1) sm += __shfl_xor(sm, off);
    s[(size_t)gw * QL + lane] = e / sm;
    if (lane == 0) smax[gw] = mx;
}

// ---------------------------------------------------------------------------
__global__ __launch_bounds__(512)
void bw_k(const float* __restrict__ smax, float* __restrict__ bw)
{
    int b = blockIdx.x, c = threadIdx.x;
    int lane = c & 63, wid = c >> 6;
    __shared__ float red[8];
    float v = smax[b * CL + c];
    float mx = v;
#pragma unroll
    for (int off = 32; off; off >>= 1) mx = fmaxf(mx, __shfl_xor(mx, off));
    if (lane == 0) red[wid] = mx;
    __syncthreads();
    float bm = red[0];
#pragma unroll
    for (int w = 1; w < 8; ++w) bm = fmaxf(bm, red[w]);
    float e = expf(v - bm);
    float sm = e;
#pragma unroll
    for (int off = 32; off; off >>= 1) sm += __shfl_xor(sm, off);
    __syncthreads();
    if (lane == 0) red[wid] = sm;
    __syncthreads();
    float ts = 0.f;
#pragma unroll
    for (int w = 0; w < 8; ++w) ts += red[w];
    bw[b * CL + c] = e / ts;
}

// ---------------------------------------------------------------------------
__global__ __launch_bounds__(256)
void q2c_k(const float* __restrict__ bw, const float* __restrict__ co,
           float* __restrict__ q2c)
{
    int b = blockIdx.x, d = threadIdx.x;
    float acc = 0.f;
    for (int c = 0; c < CL; ++c)
        acc += bw[b * CL + c] * co[((size_t)b * CL + c) * 256 + d];
    q2c[b * 256 + d] = acc;
}

// ---------------------------------------------------------------------------
__global__ __launch_bounds__(256)
void c2q_g(const float* __restrict__ a, const float* __restrict__ qo,
           const float* __restrict__ co, const float* __restrict__ q2c,
           float* __restrict__ g)
{
    int b  = blockIdx.x;
    int c  = blockIdx.y * 64 + (threadIdx.x >> 2);
    int gq = threadIdx.x & 3;

    float4 acc[16];
#pragma unroll
    for (int jj = 0; jj < 16; ++jj) acc[jj] = make_float4(0.f, 0.f, 0.f, 0.f);

    const float* ar = a + ((size_t)b * CL + c) * QL;
    for (int q = 0; q < QL; ++q) {
        float av = ar[q];
        const float* qr = qo + ((size_t)b * QL + q) * 256;
#pragma unroll
        for (int jj = 0; jj < 16; ++jj) {
            float4 qv = *(const float4*)&qr[4 * gq + 16 * jj];
            acc[jj].x += av * qv.x; acc[jj].y += av * qv.y;
            acc[jj].z += av * qv.z; acc[jj].w += av * qv.w;
        }
    }
    size_t gbase = ((size_t)b * CL + c) * 1024;
    const float* corow = co + ((size_t)b * CL + c) * 256;
    const float* q2cr  = q2c + b * 256;
#pragma unroll
    for (int jj = 0; jj < 16; ++jj) {
        int d = 4 * gq + 16 * jj;
        float4 cv = *(const float4*)&corow[d];
        float4 qc = *(const float4*)&q2cr[d];
        float4 cq = acc[jj];
        *(float4*)&g[gbase + d] = cv;
        *(float4*)&g[gbase + 256 + d] = cq;
        float4 t;
        t.x = cv.x * cq.x; t.y = cv.y * cq.y; t.z = cv.z * cq.z; t.w = cv.w * cq.w;
        *(float4*)&g[gbase + 512 + d] = t;
        t.x = cv.x * qc.x; t.y = cv.y * qc.y; t.z = cv.z * qc.z; t.w = cv.w * qc.w;
        *(float4*)&g[gbase + 768 + d] = t;
    }
}

// ---------------------------------------------------------------------------
__global__ void logits_k(const float* __restrict__ g, const float* __restrict__ m,
                         const float* __restrict__ m2o,
                         const float* __restrict__ p1wg, const float* __restrict__ p1wm,
                         const float* __restrict__ p1b,
                         const float* __restrict__ p2wg, const float* __restrict__ p2wm,
                         const float* __restrict__ p2b,
                         float* __restrict__ lp1, float* __restrict__ lp2)
{
    int row  = (int)((blockIdx.x * blockDim.x + threadIdx.x) >> 6);
    int lane = threadIdx.x & 63;
    const float* gr = g + (size_t)row * 1024;
    float s1 = 0.f, s2 = 0.f;
    for (int d = lane; d < 1024; d += 64) {
        float gv = gr[d];
        s1 += gv * p1wg[d];
        s2 += gv * p2wg[d];
    }
    const float* mr  = m   + (size_t)row * 256;
    const float* m2r = m2o + (size_t)row * 256;
    for (int d = lane; d < 256; d += 64) {
        s1 += mr[d] * p1wm[d];
        s2 += m2r[d] * p2wm[d];
    }
#pragma unroll
    for (int off = 32; off; off >>= 1) {
        s1 += __shfl_down(s1, off);
        s2 += __shfl_down(s2, off);
    }
    if (lane == 0) {
        lp1[row] = s1 + p1b[0];
        lp2[row] = s2 + p2b[0];
    }
}

// ---------------------------------------------------------------------------
__global__ __launch_bounds__(512)
void masked_softmax(const float* __restrict__ lp1, const float* __restrict__ lp2,
                    const int* __restrict__ p, float* __restrict__ out)
{
    int b = blockIdx.x, c = threadIdx.x;
    int lane = c & 63, wid = c >> 6;
    const float* lp = blockIdx.y ? lp2 : lp1;
    float* o = out + (size_t)blockIdx.y * BB * CL;

    __shared__ float red[8];
    float v = (p[b * CL + c] != 0) ? lp[b * CL + c] : -INFINITY;
    float mx = v;
#pragma unroll
    for (int off = 32; off; off >>= 1) mx = fmaxf(mx, __shfl_xor(mx, off));
    if (lane == 0) red[wid] = mx;
    __syncthreads();
    float bm = red[0];
#pragma unroll
    for (int w = 1; w < 8; ++w) bm = fmaxf(bm, red[w]);
    float e = expf(v - bm);
    float sm = e;
#pragma unroll
    for (int off = 32; off; off >>= 1) sm += __shfl_xor(sm, off);
    __syncthreads();
    if (lane == 0) red[wid] = sm;
    __syncthreads();
    float ts = 0.f;
#pragma unroll
    for (int w = 0; w < 8; ++w) ts += red[w];
    o[b * CL + c] = e / ts;
}

// ---------------------------------------------------------------------------
extern "C" void kernel_launch(void* const* d_in, const int* in_sizes, int n_in,
                              void* d_out, int out_size, void* d_ws, size_t ws_size,
                              hipStream_t stream)
{
    const int*   p        = (const int*)d_in[0];
    const int*   q        = (const int*)d_in[1];
    const float* emb      = (const float*)d_in[2];
    const float* qenc_Wih = (const float*)d_in[3];
    const float* qenc_Whh = (const float*)d_in[4];
    const float* qenc_b   = (const float*)d_in[5];
    const float* penc_Wih = (const float*)d_in[6];
    const float* penc_Whh = (const float*)d_in[7];
    const float* penc_b   = (const float*)d_in[8];
    const float* m1_Wih   = (const float*)d_in[9];
    const float* m1_Whh   = (const float*)d_in[10];
    const float* m1_b     = (const float*)d_in[11];
    const float* m2_Wih   = (const float*)d_in[12];
    const float* m2_Whh   = (const float*)d_in[13];
    const float* m2_b     = (const float*)d_in[14];
    const float* out_Wih  = (const float*)d_in[15];
    const float* out_Whh  = (const float*)d_in[16];
    const float* out_b    = (const float*)d_in[17];
    const float* att_wc   = (const float*)d_in[18];
    const float* att_wq   = (const float*)d_in[19];
    const float* att_wcq  = (const float*)d_in[20];
    const float* att_b    = (const float*)d_in[21];
    const float* p1_wg    = (const float*)d_in[22];
    const float* p1_wm    = (const float*)d_in[23];
    const float* p1_b     = (const float*)d_in[24];
    const float* p2_wg    = (const float*)d_in[25];
    const float* p2_wm    = (const float*)d_in[26];
    const float* p2_b     = (const float*)d_in[27];

    float* ws = (float*)d_ws;
    size_t off = 0;
    auto alloc = [&](size_t n) { float* r = ws + off; off += n; return r; };
    auto allocU = [&](size_t nsh) { ushort* r = (ushort*)(ws + off); off += (nsh + 1) / 2; return r; };

    const size_t NC = (size_t)BB * CL;     // 32768
    const size_t NQ = (size_t)BB * QL;     // 4096

    float* xgA  = alloc(2 * NC * GATES);   // gate preacts, reused per layer
    float* gbuf = alloc(NC * 1024);        // g  (xgQ aliases its head: dead before g written)
    float* xgQ  = gbuf;
    float* co   = alloc(NC * 256);
    float* qo   = alloc(NQ * 256);
    float* sbuf = alloc(NC * QL);          // s, then a (in place)
    float* cw   = alloc(NC);
    float* qw   = alloc(NQ);
    float* smax = alloc(NC);
    float* bw   = alloc(NC);
    float* q2c  = alloc((size_t)BB * 256);
    float* mmid = alloc(NC * 256);
    float* mbuf = alloc(NC * 256);
    float* m2o  = alloc(NC * 256);
    float* lp1  = alloc(NC);
    float* lp2  = alloc(NC);
    // bf16 weight planes: [3][1024][Ksp]
    ushort* WqP  = allocU((size_t)3 * 1024 * 320);
    ushort* WpP  = allocU((size_t)3 * 1024 * 320);
    ushort* Wm1P = allocU((size_t)3 * 1024 * 1024);
    ushort* Wm2P = allocU((size_t)3 * 1024 * 256);
    ushort* WoP  = allocU((size_t)3 * 1024 * 256);
    (void)ws_size; (void)in_sizes; (void)n_in; (void)out_size;

    // ---- weight splits ----
    splitW_k<<<dim3(1024 * 80 / 256), 256, 0, stream>>>(qenc_Wih, WqP, 300, 320);
    splitW_k<<<dim3(1024 * 80 / 256), 256, 0, stream>>>(penc_Wih, WpP, 300, 320);
    splitW_k<<<dim3(1024 * 256 / 256), 256, 0, stream>>>(m1_Wih, Wm1P, 1024, 1024);
    splitW_k<<<dim3(1024 * 64 / 256), 256, 0, stream>>>(m2_Wih, Wm2P, 256, 256);
    splitW_k<<<dim3(1024 * 64 / 256), 256, 0, stream>>>(out_Wih, WoP, 256, 256);

    // ---- encoders (P and Q scans in one launch via z) ----
    gemm_bf16x3<<<dim3(8, (int)(NQ / TM)), 256, 0, stream>>>(emb, q, WqP, qenc_b, xgQ, (int)NQ, 300, 320);
    gemm_bf16x3<<<dim3(8, (int)(NC / TM)), 256, 0, stream>>>(emb, p, WpP, penc_b, xgA, (int)NC, 300, 320);
    lstm_dpp<<<dim3(BB, 2, 2), 512, 0, stream>>>(xgA, penc_Whh, co, CL,
                                                 xgQ, qenc_Whh, qo, QL);

    // ---- attention ----
    rowdot<<<dim3((int)(NC * 64 / 256)), 256, 0, stream>>>(co, att_wc, cw, (int)NC, 256);
    rowdot<<<dim3((int)(NQ * 64 / 256)), 256, 0, stream>>>(qo, att_wq, qw, (int)NQ, 256);
    att_s<<<dim3(BB, CL / 64), 256, 0, stream>>>(co, qo, cw, qw, att_wcq, att_b, sbuf);
    softmax_q<<<dim3((int)(NC * 64 / 256)), 256, 0, stream>>>(sbuf, smax);
    bw_k<<<dim3(BB), 512, 0, stream>>>(smax, bw);
    q2c_k<<<dim3(BB), 256, 0, stream>>>(bw, co, q2c);
    c2q_g<<<dim3(BB, CL / 64), 256, 0, stream>>>(sbuf, qo, co, q2c, gbuf);

    // ---- modeling layers ----
    gemm_bf16x3<<<dim3(8, (int)(NC / TM)), 256, 0, stream>>>(gbuf, nullptr, Wm1P, m1_b, xgA, (int)NC, 1024, 1024);
    lstm_dpp<<<dim3(BB, 2, 1), 512, 0, stream>>>(xgA, m1_Whh, mmid, CL,
                                                 xgA, m1_Whh, mmid, CL);
    gemm_bf16x3<<<dim3(8, (int)(NC / TM)), 256, 0, stream>>>(mmid, nullptr, Wm2P, m2_b, xgA, (int)NC, 256, 256);
    lstm_dpp<<<dim3(BB, 2, 1), 512, 0, stream>>>(xgA, m2_Whh, mbuf, CL,
                                                 xgA, m2_Whh, mbuf, CL);
    gemm_bf16x3<<<dim3(8, (int)(NC / TM)), 256, 0, stream>>>(mbuf, nullptr, WoP, out_b, xgA, (int)NC, 256, 256);
    lstm_dpp<<<dim3(BB, 2, 1), 512, 0, stream>>>(xgA, out_Whh, m2o, CL,
                                                 xgA, out_Whh, m2o, CL);

    // ---- output ----
    logits_k<<<dim3((int)(NC * 64 / 256)), 256, 0, stream>>>(gbuf, mbuf, m2o,
        p1_wg, p1_wm, p1_b, p2_wg, p2_wm, p2_b, lp1, lp2);
    masked_softmax<<<dim3(BB, 2), 512, 0, stream>>>(lp1, lp2, p, (float*)d_out);
}